// Round 1
// baseline (15996.043 us; speedup 1.0000x reference)
//
#include <hip/hip_runtime.h>
#include <hip/hip_bf16.h>

// ---------------- problem constants ----------------
#define B 8
#define TL 512            // latent sequence length
#define M_ROWS (B * TL)   // 4096
#define D 1024            // d_model
#define DFF 1024
#define H 8
#define DH 128
#define NL 6

// ---------------- GEMM: C = A(MxK) @ W(NxK)^T + bias, optional exact GELU ---
#define BM 64
#define BN 64
#define BK 16
#define LDT (BM + 4)   // pad 4 floats: rows stay 16B aligned, write conflicts 2-way (free)

__device__ __forceinline__ float gelu_exact(float x) {
    return 0.5f * x * (1.0f + erff(x * 0.70710678118654752f));
}

__global__ __launch_bounds__(256) void gemm_nt(const float* __restrict__ A,
                                               const float* __restrict__ W,
                                               const float* __restrict__ bias,
                                               float* __restrict__ C,
                                               int M, int N, int K, int do_gelu) {
    __shared__ float As[BK][LDT];
    __shared__ float Ws[BK][LDT];
    const int bm = blockIdx.y * BM;
    const int bn = blockIdx.x * BN;
    const int tid = threadIdx.x;
    const int lrow = tid >> 2;          // 0..63
    const int lcol = (tid & 3) << 2;    // 0,4,8,12
    const int tx = tid & 15;            // n sub-tile
    const int ty = tid >> 4;            // m sub-tile

    const float* Aptr = A + (size_t)(bm + lrow) * K + lcol;
    const float* Wptr = W + (size_t)(bn + lrow) * K + lcol;

    float acc[4][4];
#pragma unroll
    for (int i = 0; i < 4; ++i)
#pragma unroll
        for (int j = 0; j < 4; ++j) acc[i][j] = 0.f;

    for (int k0 = 0; k0 < K; k0 += BK) {
        float4 a4 = *(const float4*)(Aptr + k0);
        float4 w4 = *(const float4*)(Wptr + k0);
        As[lcol + 0][lrow] = a4.x;
        As[lcol + 1][lrow] = a4.y;
        As[lcol + 2][lrow] = a4.z;
        As[lcol + 3][lrow] = a4.w;
        Ws[lcol + 0][lrow] = w4.x;
        Ws[lcol + 1][lrow] = w4.y;
        Ws[lcol + 2][lrow] = w4.z;
        Ws[lcol + 3][lrow] = w4.w;
        __syncthreads();
#pragma unroll
        for (int kk = 0; kk < BK; ++kk) {
            float am[4], wn[4];
            *(float4*)am = *(const float4*)&As[kk][ty * 4];
            *(float4*)wn = *(const float4*)&Ws[kk][tx * 4];
#pragma unroll
            for (int i = 0; i < 4; ++i)
#pragma unroll
                for (int j = 0; j < 4; ++j)
                    acc[i][j] = fmaf(am[i], wn[j], acc[i][j]);
        }
        __syncthreads();
    }

    float bv[4];
#pragma unroll
    for (int j = 0; j < 4; ++j) bv[j] = bias[bn + tx * 4 + j];

#pragma unroll
    for (int i = 0; i < 4; ++i) {
        float4 o;
        float* po = (float*)&o;
#pragma unroll
        for (int j = 0; j < 4; ++j) {
            float v = acc[i][j] + bv[j];
            po[j] = do_gelu ? gelu_exact(v) : v;
        }
        *(float4*)(C + (size_t)(bm + ty * 4 + i) * N + bn + tx * 4) = o;
    }
}

// ---------------- attention: one block per (query i, b*H+h) ----------------
// qkv: (M_ROWS, 3*D) rows; q cols [0,1024), k [1024,2048), v [2048,3072)
__global__ __launch_bounds__(128) void attn_kernel(const float* __restrict__ qkv,
                                                   float* __restrict__ att_out) {
    const int i = blockIdx.x;            // query index within sequence
    const int bh = blockIdx.y;
    const int b = bh >> 3;
    const int h = bh & 7;
    const int tid = threadIdx.x;

    __shared__ float q[DH];
    __shared__ float p[TL];
    __shared__ float red[2];

    const float scale = 0.08838834764831845f;  // 1/sqrt(128)
    const float slope = exp2f(-(float)(h + 1)); // ALiBi slope 2^-(h+1)

    const size_t qrow = ((size_t)(b * TL + i)) * (3 * D) + h * DH;
    q[tid] = qkv[qrow + tid] * scale;
    __syncthreads();

    // scores
    float lmax = -1e30f;
    for (int j = tid; j < TL; j += 128) {
        const float* krow = qkv + ((size_t)(b * TL + j)) * (3 * D) + D + h * DH;
        float dot = 0.f;
#pragma unroll 8
        for (int d = 0; d < DH; ++d) dot = fmaf(q[d], krow[d], dot);
        dot -= slope * fabsf((float)(i - j));
        p[j] = dot;
        lmax = fmaxf(lmax, dot);
    }
    // block max (2 waves)
    for (int off = 32; off; off >>= 1) lmax = fmaxf(lmax, __shfl_down(lmax, off));
    if ((tid & 63) == 0) red[tid >> 6] = lmax;
    __syncthreads();
    const float m = fmaxf(red[0], red[1]);
    __syncthreads();

    float lsum = 0.f;
    for (int j = tid; j < TL; j += 128) {
        float e = __expf(p[j] - m);
        p[j] = e;
        lsum += e;
    }
    for (int off = 32; off; off >>= 1) lsum += __shfl_down(lsum, off);
    if ((tid & 63) == 0) red[tid >> 6] = lsum;
    __syncthreads();                       // also guarantees all p[] written
    const float rinv = 1.f / (red[0] + red[1]);

    // O = p @ V ; thread owns dim d = tid
    float acc = 0.f;
    const float* vbase = qkv + 2 * D + h * DH + tid;
#pragma unroll 4
    for (int j = 0; j < TL; ++j) {
        acc = fmaf(p[j], vbase[((size_t)(b * TL + j)) * (3 * D)], acc);
    }
    att_out[((size_t)(b * TL + i)) * D + h * DH + tid] = acc * rinv;
}

// ---------------- fused residual + LayerNorm (row = 1024) ------------------
__global__ __launch_bounds__(256) void add_ln(const float* __restrict__ x,
                                              const float* __restrict__ y,
                                              const float* __restrict__ g,
                                              const float* __restrict__ bta,
                                              float* __restrict__ out) {
    __shared__ float red[4];
    const int row = blockIdx.x;
    const int tid = threadIdx.x;
    const size_t base = (size_t)row * D + tid * 4;

    float4 xv = *(const float4*)(x + base);
    float4 yv = *(const float4*)(y + base);
    float v[4] = {xv.x + yv.x, xv.y + yv.y, xv.z + yv.z, xv.w + yv.w};

    float s = v[0] + v[1] + v[2] + v[3];
    for (int off = 32; off; off >>= 1) s += __shfl_down(s, off);
    if ((tid & 63) == 0) red[tid >> 6] = s;
    __syncthreads();
    const float mean = (red[0] + red[1] + red[2] + red[3]) * (1.f / (float)D);
    __syncthreads();

    float d0 = v[0] - mean, d1 = v[1] - mean, d2 = v[2] - mean, d3 = v[3] - mean;
    float sq = d0 * d0 + d1 * d1 + d2 * d2 + d3 * d3;
    for (int off = 32; off; off >>= 1) sq += __shfl_down(sq, off);
    if ((tid & 63) == 0) red[tid >> 6] = sq;
    __syncthreads();
    const float var = (red[0] + red[1] + red[2] + red[3]) * (1.f / (float)D);
    const float inv = rsqrtf(var + 1e-5f);

    float4 gv = *(const float4*)(g + tid * 4);
    float4 bv = *(const float4*)(bta + tid * 4);
    float4 o;
    o.x = d0 * inv * gv.x + bv.x;
    o.y = d1 * inv * gv.y + bv.y;
    o.z = d2 * inv * gv.z + bv.z;
    o.w = d3 * inv * gv.w + bv.w;
    *(float4*)(out + base) = o;
}

// ---------------- launcher -------------------------------------------------
extern "C" void kernel_launch(void* const* d_in, const int* in_sizes, int n_in,
                              void* d_out, int out_size, void* d_ws, size_t ws_size,
                              hipStream_t stream) {
    const float* x_in   = (const float*)d_in[0];   // (8,2048,128) == (4096,512)
    const float* pre_w  = (const float*)d_in[1];   // (1024,512)
    const float* pre_b  = (const float*)d_in[2];
    const float* in_w   = (const float*)d_in[3];   // (6,3072,1024)
    const float* in_b   = (const float*)d_in[4];   // (6,3072)
    const float* out_w  = (const float*)d_in[5];   // (6,1024,1024)
    const float* out_b  = (const float*)d_in[6];
    const float* ln1_g  = (const float*)d_in[7];
    const float* ln1_b  = (const float*)d_in[8];
    const float* ff1_w  = (const float*)d_in[9];   // (6,1024,1024)
    const float* ff1_b  = (const float*)d_in[10];
    const float* ff2_w  = (const float*)d_in[11];
    const float* ff2_b  = (const float*)d_in[12];
    const float* ln2_g  = (const float*)d_in[13];
    const float* ln2_b  = (const float*)d_in[14];
    const float* post_w = (const float*)d_in[15];  // (1024,1024)
    const float* post_b = (const float*)d_in[16];

    float* ws  = (float*)d_ws;
    float* X   = ws;                              // 4096*1024
    float* QKV = X + (size_t)M_ROWS * D;          // 4096*3072
    float* ATT = QKV + (size_t)M_ROWS * 3 * D;    // 4096*1024
    float* Y   = ATT + (size_t)M_ROWS * D;        // 4096*1024

    const dim3 blk(256);
    const dim3 gD(D / BN, M_ROWS / BM);           // N=1024 gemms
    const dim3 gQKV(3 * D / BN, M_ROWS / BM);     // N=3072

    // pre-projection: (4096,512) @ (1024,512)^T
    gemm_nt<<<gD, blk, 0, stream>>>(x_in, pre_w, pre_b, X, M_ROWS, D, 512, 0);

    for (int l = 0; l < NL; ++l) {
        const float* iw = in_w + (size_t)l * 3 * D * D;
        const float* ib = in_b + (size_t)l * 3 * D;
        const float* ow = out_w + (size_t)l * D * D;
        const float* ob = out_b + (size_t)l * D;
        const float* f1w = ff1_w + (size_t)l * DFF * D;
        const float* f1b = ff1_b + (size_t)l * DFF;
        const float* f2w = ff2_w + (size_t)l * D * DFF;
        const float* f2b = ff2_b + (size_t)l * D;

        gemm_nt<<<gQKV, blk, 0, stream>>>(X, iw, ib, QKV, M_ROWS, 3 * D, D, 0);
        attn_kernel<<<dim3(TL, B * H), dim3(128), 0, stream>>>(QKV, ATT);
        gemm_nt<<<gD, blk, 0, stream>>>(ATT, ow, ob, Y, M_ROWS, D, D, 0);
        add_ln<<<dim3(M_ROWS), blk, 0, stream>>>(X, Y, ln1_g + (size_t)l * D,
                                                 ln1_b + (size_t)l * D, X);
        gemm_nt<<<gD, blk, 0, stream>>>(X, f1w, f1b, ATT, M_ROWS, DFF, D, 1);
        gemm_nt<<<gD, blk, 0, stream>>>(ATT, f2w, f2b, Y, M_ROWS, D, DFF, 0);
        add_ln<<<dim3(M_ROWS), blk, 0, stream>>>(X, Y, ln2_g + (size_t)l * D,
                                                 ln2_b + (size_t)l * D, X);
    }

    gemm_nt<<<gD, blk, 0, stream>>>(X, post_w, post_b, (float*)d_out,
                                    M_ROWS, D, D, 0);
}

// Round 3
// 5707.542 us; speedup vs baseline: 2.8026x; 2.8026x over previous
//
#include <hip/hip_runtime.h>
#include <hip/hip_bf16.h>

// ---------------- problem constants ----------------
#define B 8
#define TL 512            // latent sequence length
#define M_ROWS (B * TL)   // 4096
#define D 1024            // d_model
#define DFF 1024
#define H 8
#define DH 128
#define NL 6

typedef unsigned short ushort_t;
typedef unsigned int uint_t;

// ---------------- GEMM: C = A(MxK) @ W(NxK)^T + bias, optional exact GELU ---
#define BM 64
#define BN 64
#define BK 16
#define LDT (BM + 4)

__device__ __forceinline__ float gelu_exact(float x) {
    return 0.5f * x * (1.0f + erff(x * 0.70710678118654752f));
}

__global__ __launch_bounds__(256) void gemm_nt(const float* __restrict__ A,
                                               const float* __restrict__ W,
                                               const float* __restrict__ bias,
                                               float* __restrict__ C,
                                               int M, int N, int K, int do_gelu) {
    __shared__ float As[BK][LDT];
    __shared__ float Ws[BK][LDT];
    const int bm = blockIdx.y * BM;
    const int bn = blockIdx.x * BN;
    const int tid = threadIdx.x;
    const int lrow = tid >> 2;
    const int lcol = (tid & 3) << 2;
    const int tx = tid & 15;
    const int ty = tid >> 4;

    const float* Aptr = A + (size_t)(bm + lrow) * K + lcol;
    const float* Wptr = W + (size_t)(bn + lrow) * K + lcol;

    float acc[4][4];
#pragma unroll
    for (int i = 0; i < 4; ++i)
#pragma unroll
        for (int j = 0; j < 4; ++j) acc[i][j] = 0.f;

    for (int k0 = 0; k0 < K; k0 += BK) {
        float4 a4 = *(const float4*)(Aptr + k0);
        float4 w4 = *(const float4*)(Wptr + k0);
        As[lcol + 0][lrow] = a4.x;
        As[lcol + 1][lrow] = a4.y;
        As[lcol + 2][lrow] = a4.z;
        As[lcol + 3][lrow] = a4.w;
        Ws[lcol + 0][lrow] = w4.x;
        Ws[lcol + 1][lrow] = w4.y;
        Ws[lcol + 2][lrow] = w4.z;
        Ws[lcol + 3][lrow] = w4.w;
        __syncthreads();
#pragma unroll
        for (int kk = 0; kk < BK; ++kk) {
            float am[4], wn[4];
            *(float4*)am = *(const float4*)&As[kk][ty * 4];
            *(float4*)wn = *(const float4*)&Ws[kk][tx * 4];
#pragma unroll
            for (int i = 0; i < 4; ++i)
#pragma unroll
                for (int j = 0; j < 4; ++j)
                    acc[i][j] = fmaf(am[i], wn[j], acc[i][j]);
        }
        __syncthreads();
    }

    float bv[4];
#pragma unroll
    for (int j = 0; j < 4; ++j) bv[j] = bias[bn + tx * 4 + j];

#pragma unroll
    for (int i = 0; i < 4; ++i) {
        float4 o;
        float* po = (float*)&o;
#pragma unroll
        for (int j = 0; j < 4; ++j) {
            float v = acc[i][j] + bv[j];
            po[j] = do_gelu ? gelu_exact(v) : v;
        }
        *(float4*)(C + (size_t)(bm + ty * 4 + i) * N + bn + tx * 4) = o;
    }
}

// ---------------- tiled flash attention ------------------------------------
// grid (TL/64, B*H), block 256. Each block: 64 queries x full Dh=128 output.
// LDS: Qs swizzled [64][128] fp32, KV union (K swizzled [64][128] / V [64][132]),
// Ps bf16 [64][68]. Total 73.5 KB -> 2 blocks/CU.
// swizzle: float4-quad index q stored at q ^ ((row>>2)&7) -> staging writes and
// fragment reads both <=2-way bank conflicts (free).

__device__ __forceinline__ ushort_t f2bf(float f) {
    uint_t u = __float_as_uint(f);
    u += 0x7FFFu + ((u >> 16) & 1u);
    return (ushort_t)(u >> 16);
}
__device__ __forceinline__ float bf2f(ushort_t h) {
    return __uint_as_float(((uint_t)h) << 16);
}

#define SWZ(row, colq) (((row) << 7) + ((((colq) ^ (((row) >> 2) & 7))) << 2))

__global__ __launch_bounds__(256, 2) void attn_tiled(const float* __restrict__ qkv,
                                                     float* __restrict__ att_out) {
    __shared__ float Qs[64 * 128];
    __shared__ float KV[64 * 132];
    __shared__ ushort_t Ps[64 * 68];

    const int q0 = blockIdx.x * 64;
    const int bh = blockIdx.y;
    const int b = bh >> 3;
    const int h = bh & 7;
    const int tid = threadIdx.x;
    const int tx = tid & 15;   // S-col group / O-col group
    const int ty = tid >> 4;   // row group (4 rows)

    const float scale = 0.08838834764831845f;   // 1/sqrt(128)
    const float slope = exp2f(-(float)(h + 1)); // ALiBi slope

    const size_t row_stride = 3 * D;
    const float* qbase = qkv + (size_t)(b * TL) * row_stride + h * DH;

    // ---- stage Q (pre-scaled), swizzled ----
#pragma unroll
    for (int t = 0; t < 8; ++t) {
        int idx = t * 256 + tid;
        int r = idx >> 5;        // 0..63
        int c4 = idx & 31;       // quad 0..31
        float4 g = *(const float4*)(qbase + (size_t)(q0 + r) * row_stride + c4 * 4);
        float* dst = &Qs[SWZ(r, c4)];
        dst[0] = g.x * scale; dst[1] = g.y * scale;
        dst[2] = g.z * scale; dst[3] = g.w * scale;
    }

    float o[4][8];
    float m_i[4], l_i[4];
#pragma unroll
    for (int i = 0; i < 4; ++i) {
        m_i[i] = -1e30f;
        l_i[i] = 0.f;
#pragma unroll
        for (int c = 0; c < 8; ++c) o[i][c] = 0.f;
    }

    for (int kt = 0; kt < TL / 64; ++kt) {
        __syncthreads();  // prev PV / Q staging done
        // ---- stage K tile (swizzled) ----
        const float* kbase = qkv + (size_t)(b * TL + kt * 64) * row_stride + D + h * DH;
#pragma unroll
        for (int t = 0; t < 8; ++t) {
            int idx = t * 256 + tid;
            int r = idx >> 5;
            int c4 = idx & 31;
            float4 g = *(const float4*)(kbase + (size_t)r * row_stride + c4 * 4);
            *(float4*)&KV[SWZ(r, c4)] = g;
        }
        __syncthreads();

        // ---- S = Q K^T (64 FMA per 8 b128 reads) ----
        float s[4][4];
#pragma unroll
        for (int i = 0; i < 4; ++i)
#pragma unroll
            for (int j = 0; j < 4; ++j) s[i][j] = 0.f;

        for (int kk = 0; kk < DH; kk += 4) {
            const int q4 = kk >> 2;
            float4 qf[4], kf[4];
#pragma unroll
            for (int i = 0; i < 4; ++i)
                qf[i] = *(const float4*)&Qs[SWZ(4 * ty + i, q4)];
#pragma unroll
            for (int j = 0; j < 4; ++j)
                kf[j] = *(const float4*)&KV[SWZ(4 * tx + j, q4)];
#pragma unroll
            for (int i = 0; i < 4; ++i)
#pragma unroll
                for (int j = 0; j < 4; ++j) {
                    s[i][j] = fmaf(qf[i].x, kf[j].x, s[i][j]);
                    s[i][j] = fmaf(qf[i].y, kf[j].y, s[i][j]);
                    s[i][j] = fmaf(qf[i].z, kf[j].z, s[i][j]);
                    s[i][j] = fmaf(qf[i].w, kf[j].w, s[i][j]);
                }
        }

        // ---- ALiBi bias + online softmax ----
        const int gi0 = q0 + 4 * ty;
        const int gj0 = kt * 64 + 4 * tx;
        float al[4];
#pragma unroll
        for (int i = 0; i < 4; ++i) {
#pragma unroll
            for (int j = 0; j < 4; ++j)
                s[i][j] -= slope * fabsf((float)(gi0 + i - gj0 - j));
            float mn = fmaxf(fmaxf(s[i][0], s[i][1]), fmaxf(s[i][2], s[i][3]));
            mn = fmaxf(mn, __shfl_xor(mn, 1));
            mn = fmaxf(mn, __shfl_xor(mn, 2));
            mn = fmaxf(mn, __shfl_xor(mn, 4));
            mn = fmaxf(mn, __shfl_xor(mn, 8));
            float mnew = fmaxf(m_i[i], mn);
            al[i] = __expf(m_i[i] - mnew);
            float rs = 0.f;
#pragma unroll
            for (int j = 0; j < 4; ++j) {
                s[i][j] = __expf(s[i][j] - mnew);
                rs += s[i][j];
            }
            rs += __shfl_xor(rs, 1);
            rs += __shfl_xor(rs, 2);
            rs += __shfl_xor(rs, 4);
            rs += __shfl_xor(rs, 8);
            l_i[i] = l_i[i] * al[i] + rs;
            m_i[i] = mnew;
#pragma unroll
            for (int c = 0; c < 8; ++c) o[i][c] *= al[i];
        }

        // ---- store P tile as bf16 ----
#pragma unroll
        for (int i = 0; i < 4; ++i) {
            ushort4 pk;
            pk.x = f2bf(s[i][0]); pk.y = f2bf(s[i][1]);
            pk.z = f2bf(s[i][2]); pk.w = f2bf(s[i][3]);
            *(ushort4*)&Ps[(4 * ty + i) * 68 + tx * 4] = pk;
        }
        __syncthreads();  // P written; S-phase K reads done

        // ---- stage V tile (natural, pad 4) ----
        const float* vbase = qkv + (size_t)(b * TL + kt * 64) * row_stride + 2 * D + h * DH;
#pragma unroll
        for (int t = 0; t < 8; ++t) {
            int idx = t * 256 + tid;
            int r = idx >> 5;
            int c4 = idx & 31;
            *(float4*)&KV[r * 132 + c4 * 4] =
                *(const float4*)(vbase + (size_t)r * row_stride + c4 * 4);
        }
        __syncthreads();

        // ---- O += P V ----
        for (int k0 = 0; k0 < 64; k0 += 4) {
            float pf[4][4];
#pragma unroll
            for (int i = 0; i < 4; ++i) {
                ushort4 pk = *(const ushort4*)&Ps[(4 * ty + i) * 68 + k0];
                pf[i][0] = bf2f(pk.x); pf[i][1] = bf2f(pk.y);
                pf[i][2] = bf2f(pk.z); pf[i][3] = bf2f(pk.w);
            }
#pragma unroll
            for (int kk = 0; kk < 4; ++kk) {
                float4 vA = *(const float4*)&KV[(k0 + kk) * 132 + tx * 8];
                float4 vB = *(const float4*)&KV[(k0 + kk) * 132 + tx * 8 + 4];
#pragma unroll
                for (int i = 0; i < 4; ++i) {
                    float pv = pf[i][kk];
                    o[i][0] = fmaf(pv, vA.x, o[i][0]);
                    o[i][1] = fmaf(pv, vA.y, o[i][1]);
                    o[i][2] = fmaf(pv, vA.z, o[i][2]);
                    o[i][3] = fmaf(pv, vA.w, o[i][3]);
                    o[i][4] = fmaf(pv, vB.x, o[i][4]);
                    o[i][5] = fmaf(pv, vB.y, o[i][5]);
                    o[i][6] = fmaf(pv, vB.z, o[i][6]);
                    o[i][7] = fmaf(pv, vB.w, o[i][7]);
                }
            }
        }
    }

    // ---- write O / l ----
#pragma unroll
    for (int i = 0; i < 4; ++i) {
        float inv = 1.f / l_i[i];
        float4 oa, ob;
        oa.x = o[i][0] * inv; oa.y = o[i][1] * inv;
        oa.z = o[i][2] * inv; oa.w = o[i][3] * inv;
        ob.x = o[i][4] * inv; ob.y = o[i][5] * inv;
        ob.z = o[i][6] * inv; ob.w = o[i][7] * inv;
        float* dst = att_out + (size_t)(b * TL + q0 + 4 * ty + i) * D + h * DH + tx * 8;
        *(float4*)dst = oa;
        *(float4*)(dst + 4) = ob;
    }
}

// ---------------- fused residual + LayerNorm (row = 1024) ------------------
__global__ __launch_bounds__(256) void add_ln(const float* __restrict__ x,
                                              const float* __restrict__ y,
                                              const float* __restrict__ g,
                                              const float* __restrict__ bta,
                                              float* __restrict__ out) {
    __shared__ float red[4];
    const int row = blockIdx.x;
    const int tid = threadIdx.x;
    const size_t base = (size_t)row * D + tid * 4;

    float4 xv = *(const float4*)(x + base);
    float4 yv = *(const float4*)(y + base);
    float v[4] = {xv.x + yv.x, xv.y + yv.y, xv.z + yv.z, xv.w + yv.w};

    float s = v[0] + v[1] + v[2] + v[3];
    for (int off = 32; off; off >>= 1) s += __shfl_down(s, off);
    if ((tid & 63) == 0) red[tid >> 6] = s;
    __syncthreads();
    const float mean = (red[0] + red[1] + red[2] + red[3]) * (1.f / (float)D);
    __syncthreads();

    float d0 = v[0] - mean, d1 = v[1] - mean, d2 = v[2] - mean, d3 = v[3] - mean;
    float sq = d0 * d0 + d1 * d1 + d2 * d2 + d3 * d3;
    for (int off = 32; off; off >>= 1) sq += __shfl_down(sq, off);
    if ((tid & 63) == 0) red[tid >> 6] = sq;
    __syncthreads();
    const float var = (red[0] + red[1] + red[2] + red[3]) * (1.f / (float)D);
    const float inv = rsqrtf(var + 1e-5f);

    float4 gv = *(const float4*)(g + tid * 4);
    float4 bv = *(const float4*)(bta + tid * 4);
    float4 o;
    o.x = d0 * inv * gv.x + bv.x;
    o.y = d1 * inv * gv.y + bv.y;
    o.z = d2 * inv * gv.z + bv.z;
    o.w = d3 * inv * gv.w + bv.w;
    *(float4*)(out + base) = o;
}

// ---------------- launcher -------------------------------------------------
extern "C" void kernel_launch(void* const* d_in, const int* in_sizes, int n_in,
                              void* d_out, int out_size, void* d_ws, size_t ws_size,
                              hipStream_t stream) {
    const float* x_in   = (const float*)d_in[0];
    const float* pre_w  = (const float*)d_in[1];
    const float* pre_b  = (const float*)d_in[2];
    const float* in_w   = (const float*)d_in[3];
    const float* in_b   = (const float*)d_in[4];
    const float* out_w  = (const float*)d_in[5];
    const float* out_b  = (const float*)d_in[6];
    const float* ln1_g  = (const float*)d_in[7];
    const float* ln1_b  = (const float*)d_in[8];
    const float* ff1_w  = (const float*)d_in[9];
    const float* ff1_b  = (const float*)d_in[10];
    const float* ff2_w  = (const float*)d_in[11];
    const float* ff2_b  = (const float*)d_in[12];
    const float* ln2_g  = (const float*)d_in[13];
    const float* ln2_b  = (const float*)d_in[14];
    const float* post_w = (const float*)d_in[15];
    const float* post_b = (const float*)d_in[16];

    float* ws  = (float*)d_ws;
    float* X   = ws;
    float* QKV = X + (size_t)M_ROWS * D;
    float* ATT = QKV + (size_t)M_ROWS * 3 * D;
    float* Y   = ATT + (size_t)M_ROWS * D;

    const dim3 blk(256);
    const dim3 gD(D / BN, M_ROWS / BM);
    const dim3 gQKV(3 * D / BN, M_ROWS / BM);

    gemm_nt<<<gD, blk, 0, stream>>>(x_in, pre_w, pre_b, X, M_ROWS, D, 512, 0);

    for (int l = 0; l < NL; ++l) {
        const float* iw = in_w + (size_t)l * 3 * D * D;
        const float* ib = in_b + (size_t)l * 3 * D;
        const float* ow = out_w + (size_t)l * D * D;
        const float* ob = out_b + (size_t)l * D;
        const float* f1w = ff1_w + (size_t)l * DFF * D;
        const float* f1b = ff1_b + (size_t)l * DFF;
        const float* f2w = ff2_w + (size_t)l * D * DFF;
        const float* f2b = ff2_b + (size_t)l * D;

        gemm_nt<<<gQKV, blk, 0, stream>>>(X, iw, ib, QKV, M_ROWS, 3 * D, D, 0);
        attn_tiled<<<dim3(TL / 64, B * H), blk, 0, stream>>>(QKV, ATT);
        gemm_nt<<<gD, blk, 0, stream>>>(ATT, ow, ob, Y, M_ROWS, D, D, 0);
        add_ln<<<dim3(M_ROWS), blk, 0, stream>>>(X, Y, ln1_g + (size_t)l * D,
                                                 ln1_b + (size_t)l * D, X);
        gemm_nt<<<gD, blk, 0, stream>>>(X, f1w, f1b, ATT, M_ROWS, DFF, D, 1);
        gemm_nt<<<gD, blk, 0, stream>>>(ATT, f2w, f2b, Y, M_ROWS, D, DFF, 0);
        add_ln<<<dim3(M_ROWS), blk, 0, stream>>>(X, Y, ln2_g + (size_t)l * D,
                                                 ln2_b + (size_t)l * D, X);
    }

    gemm_nt<<<gD, blk, 0, stream>>>(X, post_w, post_b, (float*)d_out,
                                    M_ROWS, D, D, 0);
}

// Round 4
// 2133.165 us; speedup vs baseline: 7.4987x; 2.6756x over previous
//
#include <hip/hip_runtime.h>
#include <hip/hip_bf16.h>

// ---------------- problem constants ----------------
#define B 8
#define TL 512
#define M_ROWS 4096
#define D 1024
#define DFF 1024
#define H 8
#define DH 128
#define NL 6

typedef unsigned short ushort_t;
typedef unsigned int uint_t;
typedef short bf16x8 __attribute__((ext_vector_type(8)));
typedef float f32x4 __attribute__((ext_vector_type(4)));

__device__ __forceinline__ ushort_t f2bf(float f) {
    uint_t u = __float_as_uint(f);
    u += 0x7FFFu + ((u >> 16) & 1u);
    return (ushort_t)(u >> 16);
}
__device__ __forceinline__ float bf2f(ushort_t h) {
    return __uint_as_float(((uint_t)h) << 16);
}
__device__ __forceinline__ float gelu_exact(float x) {
    return 0.5f * x * (1.0f + erff(x * 0.70710678118654752f));
}

// ---------------- f32 -> bf16 conversion -----------------------------------
__global__ __launch_bounds__(256) void cvt_bf16(const float* __restrict__ s,
                                                ushort_t* __restrict__ d, int n) {
    int stride = gridDim.x * blockDim.x;
    for (int i = blockIdx.x * blockDim.x + threadIdx.x; i * 4 < n; i += stride) {
        float4 v = *(const float4*)(s + (size_t)i * 4);
        ushort4 o;
        o.x = f2bf(v.x); o.y = f2bf(v.y); o.z = f2bf(v.z); o.w = f2bf(v.w);
        *(ushort4*)(d + (size_t)i * 4) = o;
    }
}

// ---------------- bf16 MFMA GEMM (m97 structure) ---------------------------
// C = A(MxK) @ W(NxK)^T + bias.  A, W row-major bf16 (K contiguous -> both
// operands load directly into 16x16x32 frags: elem k = (lane>>4)*8+j).
// 128x128 tile, BK=32, 4 waves, 4x4 MFMA tiles/wave.
// LDS image is contiguous (global_load_lds requirement); a 2-bit XOR swizzle
// (g ^= (row>>1)&3) is baked into WHICH global 16B chunk lands in slot s, so
// ds_read_b128 fragment reads cover 8 distinct bank-quads (2-way = free).
#define LDS_SLOT(r, g) (((r) << 2) + ((g) ^ (((r) >> 1) & 3)))

__device__ __forceinline__ void gload_lds16(const ushort_t* g, ushort_t* l) {
    __builtin_amdgcn_global_load_lds(
        (const __attribute__((address_space(1))) void*)g,
        (__attribute__((address_space(3))) void*)l, 16, 0, 0);
}

__global__ __launch_bounds__(256) void gemm_bf16(
    const ushort_t* __restrict__ A, const ushort_t* __restrict__ W,
    const float* __restrict__ bias, float* __restrict__ Cf,
    ushort_t* __restrict__ Cb, int M, int N, int K, int do_gelu) {
    __shared__ ushort_t As[128 * 32];
    __shared__ ushort_t Bs[128 * 32];

    const int tid = threadIdx.x;
    const int lane = tid & 63;
    const int w = tid >> 6;
    const int wm = (w >> 1) * 64;
    const int wn = (w & 1) * 64;
    const int bm = blockIdx.y * 128;
    const int bn = blockIdx.x * 128;

    // staging: thread handles physical slots tid and tid+256 for A and B
    const int s0 = tid, s1 = tid + 256;
    const int r0 = s0 >> 2, g0 = (s0 & 3) ^ ((r0 >> 1) & 3);
    const int r1 = s1 >> 2, g1 = (s1 & 3) ^ ((r1 >> 1) & 3);
    const ushort_t* gA0 = A + (size_t)(bm + r0) * K + g0 * 8;
    const ushort_t* gA1 = A + (size_t)(bm + r1) * K + g1 * 8;
    const ushort_t* gB0 = W + (size_t)(bn + r0) * K + g0 * 8;
    const ushort_t* gB1 = W + (size_t)(bn + r1) * K + g1 * 8;
    ushort_t* lA0 = &As[s0 * 8];
    ushort_t* lA1 = &As[s1 * 8];
    ushort_t* lB0 = &Bs[s0 * 8];
    ushort_t* lB1 = &Bs[s1 * 8];

    // fragment LDS offsets (constant across K-loop)
    const int fr = lane & 15;
    const int fq = lane >> 4;
    int aoff[4], boff[4];
#pragma unroll
    for (int t = 0; t < 4; ++t) {
        int ar = wm + t * 16 + fr;
        int br = wn + t * 16 + fr;
        aoff[t] = LDS_SLOT(ar, fq) * 8;
        boff[t] = LDS_SLOT(br, fq) * 8;
    }

    f32x4 acc[4][4];
#pragma unroll
    for (int i = 0; i < 4; ++i)
#pragma unroll
        for (int j = 0; j < 4; ++j) acc[i][j] = (f32x4){0.f, 0.f, 0.f, 0.f};

    for (int k0 = 0; k0 < K; k0 += 32) {
        gload_lds16(gA0 + k0, lA0);
        gload_lds16(gA1 + k0, lA1);
        gload_lds16(gB0 + k0, lB0);
        gload_lds16(gB1 + k0, lB1);
        __syncthreads();  // drains vmcnt before LDS reads

        bf16x8 af[4], bf[4];
#pragma unroll
        for (int t = 0; t < 4; ++t) af[t] = *(const bf16x8*)&As[aoff[t]];
#pragma unroll
        for (int t = 0; t < 4; ++t) bf[t] = *(const bf16x8*)&Bs[boff[t]];
#pragma unroll
        for (int i = 0; i < 4; ++i)
#pragma unroll
            for (int j = 0; j < 4; ++j)
                acc[i][j] = __builtin_amdgcn_mfma_f32_16x16x32_bf16(
                    af[i], bf[j], acc[i][j], 0, 0, 0);
        __syncthreads();  // protect LDS overwrite next iter
    }

    // epilogue: C/D layout col=lane&15, row=(lane>>4)*4+reg
#pragma unroll
    for (int tj = 0; tj < 4; ++tj) {
        const int n = bn + wn + tj * 16 + (lane & 15);
        const float bv = bias[n];
#pragma unroll
        for (int ti = 0; ti < 4; ++ti) {
            const int m0 = bm + wm + ti * 16 + (lane >> 4) * 4;
            f32x4 a = acc[ti][tj];
#pragma unroll
            for (int r = 0; r < 4; ++r) {
                float v = a[r] + bv;
                if (do_gelu) v = gelu_exact(v);
                const size_t off = (size_t)(m0 + r) * N + n;
                if (Cf) Cf[off] = v;
                if (Cb) Cb[off] = f2bf(v);
            }
        }
    }
}

// ---------------- tiled flash attention (fp32, + bf16 copy out) ------------
#define SWZ(row, colq) (((row) << 7) + ((((colq) ^ (((row) >> 2) & 7))) << 2))

__global__ __launch_bounds__(256, 2) void attn_tiled(const float* __restrict__ qkv,
                                                     float* __restrict__ att_out,
                                                     ushort_t* __restrict__ att_bf) {
    __shared__ float Qs[64 * 128];
    __shared__ float KV[64 * 132];
    __shared__ ushort_t Ps[64 * 68];

    const int q0 = blockIdx.x * 64;
    const int bh = blockIdx.y;
    const int b = bh >> 3;
    const int h = bh & 7;
    const int tid = threadIdx.x;
    const int tx = tid & 15;
    const int ty = tid >> 4;

    const float scale = 0.08838834764831845f;
    const float slope = exp2f(-(float)(h + 1));

    const size_t row_stride = 3 * D;
    const float* qbase = qkv + (size_t)(b * TL) * row_stride + h * DH;

#pragma unroll
    for (int t = 0; t < 8; ++t) {
        int idx = t * 256 + tid;
        int r = idx >> 5;
        int c4 = idx & 31;
        float4 g = *(const float4*)(qbase + (size_t)(q0 + r) * row_stride + c4 * 4);
        float* dst = &Qs[SWZ(r, c4)];
        dst[0] = g.x * scale; dst[1] = g.y * scale;
        dst[2] = g.z * scale; dst[3] = g.w * scale;
    }

    float o[4][8];
    float m_i[4], l_i[4];
#pragma unroll
    for (int i = 0; i < 4; ++i) {
        m_i[i] = -1e30f;
        l_i[i] = 0.f;
#pragma unroll
        for (int c = 0; c < 8; ++c) o[i][c] = 0.f;
    }

    for (int kt = 0; kt < TL / 64; ++kt) {
        __syncthreads();
        const float* kbase = qkv + (size_t)(b * TL + kt * 64) * row_stride + D + h * DH;
#pragma unroll
        for (int t = 0; t < 8; ++t) {
            int idx = t * 256 + tid;
            int r = idx >> 5;
            int c4 = idx & 31;
            float4 g = *(const float4*)(kbase + (size_t)r * row_stride + c4 * 4);
            *(float4*)&KV[SWZ(r, c4)] = g;
        }
        __syncthreads();

        float s[4][4];
#pragma unroll
        for (int i = 0; i < 4; ++i)
#pragma unroll
            for (int j = 0; j < 4; ++j) s[i][j] = 0.f;

        for (int kk = 0; kk < DH; kk += 4) {
            const int q4 = kk >> 2;
            float4 qf[4], kf[4];
#pragma unroll
            for (int i = 0; i < 4; ++i)
                qf[i] = *(const float4*)&Qs[SWZ(4 * ty + i, q4)];
#pragma unroll
            for (int j = 0; j < 4; ++j)
                kf[j] = *(const float4*)&KV[SWZ(4 * tx + j, q4)];
#pragma unroll
            for (int i = 0; i < 4; ++i)
#pragma unroll
                for (int j = 0; j < 4; ++j) {
                    s[i][j] = fmaf(qf[i].x, kf[j].x, s[i][j]);
                    s[i][j] = fmaf(qf[i].y, kf[j].y, s[i][j]);
                    s[i][j] = fmaf(qf[i].z, kf[j].z, s[i][j]);
                    s[i][j] = fmaf(qf[i].w, kf[j].w, s[i][j]);
                }
        }

        const int gi0 = q0 + 4 * ty;
        const int gj0 = kt * 64 + 4 * tx;
        float al[4];
#pragma unroll
        for (int i = 0; i < 4; ++i) {
#pragma unroll
            for (int j = 0; j < 4; ++j)
                s[i][j] -= slope * fabsf((float)(gi0 + i - gj0 - j));
            float mn = fmaxf(fmaxf(s[i][0], s[i][1]), fmaxf(s[i][2], s[i][3]));
            mn = fmaxf(mn, __shfl_xor(mn, 1));
            mn = fmaxf(mn, __shfl_xor(mn, 2));
            mn = fmaxf(mn, __shfl_xor(mn, 4));
            mn = fmaxf(mn, __shfl_xor(mn, 8));
            float mnew = fmaxf(m_i[i], mn);
            al[i] = __expf(m_i[i] - mnew);
            float rs = 0.f;
#pragma unroll
            for (int j = 0; j < 4; ++j) {
                s[i][j] = __expf(s[i][j] - mnew);
                rs += s[i][j];
            }
            rs += __shfl_xor(rs, 1);
            rs += __shfl_xor(rs, 2);
            rs += __shfl_xor(rs, 4);
            rs += __shfl_xor(rs, 8);
            l_i[i] = l_i[i] * al[i] + rs;
            m_i[i] = mnew;
#pragma unroll
            for (int c = 0; c < 8; ++c) o[i][c] *= al[i];
        }

#pragma unroll
        for (int i = 0; i < 4; ++i) {
            ushort4 pk;
            pk.x = f2bf(s[i][0]); pk.y = f2bf(s[i][1]);
            pk.z = f2bf(s[i][2]); pk.w = f2bf(s[i][3]);
            *(ushort4*)&Ps[(4 * ty + i) * 68 + tx * 4] = pk;
        }
        __syncthreads();

        const float* vbase = qkv + (size_t)(b * TL + kt * 64) * row_stride + 2 * D + h * DH;
#pragma unroll
        for (int t = 0; t < 8; ++t) {
            int idx = t * 256 + tid;
            int r = idx >> 5;
            int c4 = idx & 31;
            *(float4*)&KV[r * 132 + c4 * 4] =
                *(const float4*)(vbase + (size_t)r * row_stride + c4 * 4);
        }
        __syncthreads();

        for (int k0 = 0; k0 < 64; k0 += 4) {
            float pf[4][4];
#pragma unroll
            for (int i = 0; i < 4; ++i) {
                ushort4 pk = *(const ushort4*)&Ps[(4 * ty + i) * 68 + k0];
                pf[i][0] = bf2f(pk.x); pf[i][1] = bf2f(pk.y);
                pf[i][2] = bf2f(pk.z); pf[i][3] = bf2f(pk.w);
            }
#pragma unroll
            for (int kk = 0; kk < 4; ++kk) {
                float4 vA = *(const float4*)&KV[(k0 + kk) * 132 + tx * 8];
                float4 vB = *(const float4*)&KV[(k0 + kk) * 132 + tx * 8 + 4];
#pragma unroll
                for (int i = 0; i < 4; ++i) {
                    float pv = pf[i][kk];
                    o[i][0] = fmaf(pv, vA.x, o[i][0]);
                    o[i][1] = fmaf(pv, vA.y, o[i][1]);
                    o[i][2] = fmaf(pv, vA.z, o[i][2]);
                    o[i][3] = fmaf(pv, vA.w, o[i][3]);
                    o[i][4] = fmaf(pv, vB.x, o[i][4]);
                    o[i][5] = fmaf(pv, vB.y, o[i][5]);
                    o[i][6] = fmaf(pv, vB.z, o[i][6]);
                    o[i][7] = fmaf(pv, vB.w, o[i][7]);
                }
            }
        }
    }

#pragma unroll
    for (int i = 0; i < 4; ++i) {
        float inv = 1.f / l_i[i];
        float vo[8];
#pragma unroll
        for (int c = 0; c < 8; ++c) vo[c] = o[i][c] * inv;
        const size_t base = (size_t)(b * TL + q0 + 4 * ty + i) * D + h * DH + tx * 8;
        float* dst = att_out + base;
        *(float4*)dst = *(float4*)&vo[0];
        *(float4*)(dst + 4) = *(float4*)&vo[4];
        ushort4 ba, bb;
        ba.x = f2bf(vo[0]); ba.y = f2bf(vo[1]); ba.z = f2bf(vo[2]); ba.w = f2bf(vo[3]);
        bb.x = f2bf(vo[4]); bb.y = f2bf(vo[5]); bb.z = f2bf(vo[6]); bb.w = f2bf(vo[7]);
        *(ushort4*)(att_bf + base) = ba;
        *(ushort4*)(att_bf + base + 4) = bb;
    }
}

// ---------------- fused residual + LayerNorm (+ bf16 copy out) -------------
__global__ __launch_bounds__(256) void add_ln(const float* __restrict__ x,
                                              const float* __restrict__ y,
                                              const float* __restrict__ g,
                                              const float* __restrict__ bta,
                                              float* __restrict__ out,
                                              ushort_t* __restrict__ outb) {
    __shared__ float red[4];
    const int row = blockIdx.x;
    const int tid = threadIdx.x;
    const size_t base = (size_t)row * D + tid * 4;

    float4 xv = *(const float4*)(x + base);
    float4 yv = *(const float4*)(y + base);
    float v[4] = {xv.x + yv.x, xv.y + yv.y, xv.z + yv.z, xv.w + yv.w};

    float s = v[0] + v[1] + v[2] + v[3];
    for (int off = 32; off; off >>= 1) s += __shfl_down(s, off);
    if ((tid & 63) == 0) red[tid >> 6] = s;
    __syncthreads();
    const float mean = (red[0] + red[1] + red[2] + red[3]) * (1.f / (float)D);
    __syncthreads();

    float d0 = v[0] - mean, d1 = v[1] - mean, d2 = v[2] - mean, d3 = v[3] - mean;
    float sq = d0 * d0 + d1 * d1 + d2 * d2 + d3 * d3;
    for (int off = 32; off; off >>= 1) sq += __shfl_down(sq, off);
    if ((tid & 63) == 0) red[tid >> 6] = sq;
    __syncthreads();
    const float var = (red[0] + red[1] + red[2] + red[3]) * (1.f / (float)D);
    const float inv = rsqrtf(var + 1e-5f);

    float4 gv = *(const float4*)(g + tid * 4);
    float4 bv = *(const float4*)(bta + tid * 4);
    float4 o;
    o.x = d0 * inv * gv.x + bv.x;
    o.y = d1 * inv * gv.y + bv.y;
    o.z = d2 * inv * gv.z + bv.z;
    o.w = d3 * inv * gv.w + bv.w;
    *(float4*)(out + base) = o;
    ushort4 ob;
    ob.x = f2bf(o.x); ob.y = f2bf(o.y); ob.z = f2bf(o.z); ob.w = f2bf(o.w);
    *(ushort4*)(outb + base) = ob;
}

// ---------------- launcher -------------------------------------------------
extern "C" void kernel_launch(void* const* d_in, const int* in_sizes, int n_in,
                              void* d_out, int out_size, void* d_ws, size_t ws_size,
                              hipStream_t stream) {
    const float* x_in   = (const float*)d_in[0];
    const float* pre_w  = (const float*)d_in[1];
    const float* pre_b  = (const float*)d_in[2];
    const float* in_w   = (const float*)d_in[3];
    const float* in_b   = (const float*)d_in[4];
    const float* out_w  = (const float*)d_in[5];
    const float* out_b  = (const float*)d_in[6];
    const float* ln1_g  = (const float*)d_in[7];
    const float* ln1_b  = (const float*)d_in[8];
    const float* ff1_w  = (const float*)d_in[9];
    const float* ff1_b  = (const float*)d_in[10];
    const float* ff2_w  = (const float*)d_in[11];
    const float* ff2_b  = (const float*)d_in[12];
    const float* ln2_g  = (const float*)d_in[13];
    const float* ln2_b  = (const float*)d_in[14];
    const float* post_w = (const float*)d_in[15];
    const float* post_b = (const float*)d_in[16];

    float* X   = (float*)d_ws;                       // 4096x1024 f32
    float* QKV = X + (size_t)M_ROWS * D;             // 4096x3072 f32
    float* ATT = QKV + (size_t)M_ROWS * 3 * D;       // 4096x1024 f32
    float* Y   = ATT + (size_t)M_ROWS * D;           // 4096x1024 f32
    ushort_t* Xb   = (ushort_t*)(Y + (size_t)M_ROWS * D);  // bf16 activations
    ushort_t* Ab   = Xb + (size_t)M_ROWS * D;              // attn-out / gelu-out bf16
    ushort_t* xinb = Ab + (size_t)M_ROWS * D;              // 4096x512
    ushort_t* pwb  = xinb + (size_t)M_ROWS * 512;
    ushort_t* iwb  = pwb + (size_t)D * 512;
    ushort_t* owb  = iwb + (size_t)NL * 3 * D * D;
    ushort_t* f1wb = owb + (size_t)NL * D * D;
    ushort_t* f2wb = f1wb + (size_t)NL * DFF * D;
    ushort_t* powb = f2wb + (size_t)NL * D * DFF;

    const dim3 blk(256);
    const int cg = 1024;

    cvt_bf16<<<cg, blk, 0, stream>>>(x_in, xinb, M_ROWS * 512);
    cvt_bf16<<<cg, blk, 0, stream>>>(pre_w, pwb, D * 512);
    cvt_bf16<<<cg, blk, 0, stream>>>(in_w, iwb, NL * 3 * D * D);
    cvt_bf16<<<cg, blk, 0, stream>>>(out_w, owb, NL * D * D);
    cvt_bf16<<<cg, blk, 0, stream>>>(ff1_w, f1wb, NL * DFF * D);
    cvt_bf16<<<cg, blk, 0, stream>>>(ff2_w, f2wb, NL * D * DFF);
    cvt_bf16<<<cg, blk, 0, stream>>>(post_w, powb, D * D);

    const dim3 gD(D / 128, M_ROWS / 128);
    const dim3 gQKV(3 * D / 128, M_ROWS / 128);

    gemm_bf16<<<gD, blk, 0, stream>>>(xinb, pwb, pre_b, X, Xb,
                                      M_ROWS, D, 512, 0);

    for (int l = 0; l < NL; ++l) {
        gemm_bf16<<<gQKV, blk, 0, stream>>>(Xb, iwb + (size_t)l * 3 * D * D,
                                            in_b + (size_t)l * 3 * D, QKV, nullptr,
                                            M_ROWS, 3 * D, D, 0);
        attn_tiled<<<dim3(TL / 64, B * H), blk, 0, stream>>>(QKV, ATT, Ab);
        gemm_bf16<<<gD, blk, 0, stream>>>(Ab, owb + (size_t)l * D * D,
                                          out_b + (size_t)l * D, Y, nullptr,
                                          M_ROWS, D, D, 0);
        add_ln<<<dim3(M_ROWS), blk, 0, stream>>>(X, Y, ln1_g + (size_t)l * D,
                                                 ln1_b + (size_t)l * D, X, Xb);
        gemm_bf16<<<gD, blk, 0, stream>>>(Xb, f1wb + (size_t)l * DFF * D,
                                          ff1_b + (size_t)l * DFF, nullptr, Ab,
                                          M_ROWS, DFF, D, 1);
        gemm_bf16<<<gD, blk, 0, stream>>>(Ab, f2wb + (size_t)l * D * DFF,
                                          ff2_b + (size_t)l * D, Y, nullptr,
                                          M_ROWS, D, DFF, 0);
        add_ln<<<dim3(M_ROWS), blk, 0, stream>>>(X, Y, ln2_g + (size_t)l * D,
                                                 ln2_b + (size_t)l * D, X, Xb);
    }

    gemm_bf16<<<gD, blk, 0, stream>>>(Xb, powb, post_b, (float*)d_out, nullptr,
                                      M_ROWS, D, D, 0);
}

// Round 6
// 1391.272 us; speedup vs baseline: 11.4974x; 1.5332x over previous
//
#include <hip/hip_runtime.h>
#include <hip/hip_bf16.h>

// ---------------- problem constants ----------------
#define B 8
#define TL 512
#define M_ROWS 4096
#define D 1024
#define DFF 1024
#define H 8
#define DH 128
#define NL 6

typedef unsigned short ushort_t;
typedef unsigned int uint_t;
typedef short bf16x8 __attribute__((ext_vector_type(8)));
typedef float f32x4 __attribute__((ext_vector_type(4)));

__device__ __forceinline__ ushort_t f2bf(float f) {
    uint_t u = __float_as_uint(f);
    u += 0x7FFFu + ((u >> 16) & 1u);
    return (ushort_t)(u >> 16);
}
__device__ __forceinline__ float gelu_exact(float x) {
    return 0.5f * x * (1.0f + erff(x * 0.70710678118654752f));
}
__device__ __forceinline__ void gload_lds16(const ushort_t* g, ushort_t* l) {
    __builtin_amdgcn_global_load_lds(
        (const __attribute__((address_space(1))) void*)g,
        (__attribute__((address_space(3))) void*)l, 16, 0, 0);
}

// ---------------- f32 -> bf16 conversion -----------------------------------
__global__ __launch_bounds__(256) void cvt_bf16(const float* __restrict__ s,
                                                ushort_t* __restrict__ d, int n) {
    int stride = gridDim.x * blockDim.x;
    for (int i = blockIdx.x * blockDim.x + threadIdx.x; i * 4 < n; i += stride) {
        float4 v = *(const float4*)(s + (size_t)i * 4);
        ushort4 o;
        o.x = f2bf(v.x); o.y = f2bf(v.y); o.z = f2bf(v.z); o.w = f2bf(v.w);
        *(ushort4*)(d + (size_t)i * 4) = o;
    }
}

// ---------------- bf16 MFMA GEMM (m97 structure) ---------------------------
// C = A(MxK) @ W(NxK)^T + bias.  128x128 tile, BK=32, 4 waves, 4x4 MFMA/wave.
#define LDS_SLOT(r, g) (((r) << 2) + ((g) ^ (((r) >> 1) & 3)))

__global__ __launch_bounds__(256) void gemm_bf16(
    const ushort_t* __restrict__ A, const ushort_t* __restrict__ W,
    const float* __restrict__ bias, float* __restrict__ Cf,
    ushort_t* __restrict__ Cb, int M, int N, int K, int do_gelu) {
    __shared__ ushort_t As[128 * 32];
    __shared__ ushort_t Bs[128 * 32];

    const int tid = threadIdx.x;
    const int lane = tid & 63;
    const int w = tid >> 6;
    const int wm = (w >> 1) * 64;
    const int wn = (w & 1) * 64;
    const int bm = blockIdx.y * 128;
    const int bn = blockIdx.x * 128;

    const int s0 = tid, s1 = tid + 256;
    const int r0 = s0 >> 2, g0 = (s0 & 3) ^ ((r0 >> 1) & 3);
    const int r1 = s1 >> 2, g1 = (s1 & 3) ^ ((r1 >> 1) & 3);
    const ushort_t* gA0 = A + (size_t)(bm + r0) * K + g0 * 8;
    const ushort_t* gA1 = A + (size_t)(bm + r1) * K + g1 * 8;
    const ushort_t* gB0 = W + (size_t)(bn + r0) * K + g0 * 8;
    const ushort_t* gB1 = W + (size_t)(bn + r1) * K + g1 * 8;
    ushort_t* lA0 = &As[s0 * 8];
    ushort_t* lA1 = &As[s1 * 8];
    ushort_t* lB0 = &Bs[s0 * 8];
    ushort_t* lB1 = &Bs[s1 * 8];

    const int fr = lane & 15;
    const int fq = lane >> 4;
    int aoff[4], boff[4];
#pragma unroll
    for (int t = 0; t < 4; ++t) {
        aoff[t] = LDS_SLOT(wm + t * 16 + fr, fq) * 8;
        boff[t] = LDS_SLOT(wn + t * 16 + fr, fq) * 8;
    }

    f32x4 acc[4][4];
#pragma unroll
    for (int i = 0; i < 4; ++i)
#pragma unroll
        for (int j = 0; j < 4; ++j) acc[i][j] = (f32x4){0.f, 0.f, 0.f, 0.f};

    for (int k0 = 0; k0 < K; k0 += 32) {
        gload_lds16(gA0 + k0, lA0);
        gload_lds16(gA1 + k0, lA1);
        gload_lds16(gB0 + k0, lB0);
        gload_lds16(gB1 + k0, lB1);
        __syncthreads();

        bf16x8 af[4], bf[4];
#pragma unroll
        for (int t = 0; t < 4; ++t) af[t] = *(const bf16x8*)&As[aoff[t]];
#pragma unroll
        for (int t = 0; t < 4; ++t) bf[t] = *(const bf16x8*)&Bs[boff[t]];
#pragma unroll
        for (int i = 0; i < 4; ++i)
#pragma unroll
            for (int j = 0; j < 4; ++j)
                acc[i][j] = __builtin_amdgcn_mfma_f32_16x16x32_bf16(
                    af[i], bf[j], acc[i][j], 0, 0, 0);
        __syncthreads();
    }

#pragma unroll
    for (int tj = 0; tj < 4; ++tj) {
        const int n = bn + wn + tj * 16 + fr;
        const float bv = bias[n];
#pragma unroll
        for (int ti = 0; ti < 4; ++ti) {
            const int m0 = bm + wm + ti * 16 + fq * 4;
            f32x4 a = acc[ti][tj];
#pragma unroll
            for (int r = 0; r < 4; ++r) {
                float v = a[r] + bv;
                if (do_gelu) v = gelu_exact(v);
                const size_t off = (size_t)(m0 + r) * N + n;
                if (Cf) Cf[off] = v;
                if (Cb) Cb[off] = f2bf(v);
            }
        }
    }
}

// ---------------- QKV GEMM: bf16 out, V transposed -------------------------
__global__ __launch_bounds__(256) void gemm_qkv(
    const ushort_t* __restrict__ A, const ushort_t* __restrict__ W,
    const float* __restrict__ bias, ushort_t* __restrict__ Qb,
    ushort_t* __restrict__ Kb, ushort_t* __restrict__ Vt, int K) {
    __shared__ ushort_t As[128 * 32];
    __shared__ ushort_t Bs[128 * 32];

    const int tid = threadIdx.x;
    const int lane = tid & 63;
    const int w = tid >> 6;
    const int wm = (w >> 1) * 64;
    const int wn = (w & 1) * 64;
    const int bm = blockIdx.y * 128;
    const int bn = blockIdx.x * 128;

    const int s0 = tid, s1 = tid + 256;
    const int r0 = s0 >> 2, g0 = (s0 & 3) ^ ((r0 >> 1) & 3);
    const int r1 = s1 >> 2, g1 = (s1 & 3) ^ ((r1 >> 1) & 3);
    const ushort_t* gA0 = A + (size_t)(bm + r0) * K + g0 * 8;
    const ushort_t* gA1 = A + (size_t)(bm + r1) * K + g1 * 8;
    const ushort_t* gB0 = W + (size_t)(bn + r0) * K + g0 * 8;
    const ushort_t* gB1 = W + (size_t)(bn + r1) * K + g1 * 8;
    ushort_t* lA0 = &As[s0 * 8];
    ushort_t* lA1 = &As[s1 * 8];
    ushort_t* lB0 = &Bs[s0 * 8];
    ushort_t* lB1 = &Bs[s1 * 8];

    const int fr = lane & 15;
    const int fq = lane >> 4;
    int aoff[4], boff[4];
#pragma unroll
    for (int t = 0; t < 4; ++t) {
        aoff[t] = LDS_SLOT(wm + t * 16 + fr, fq) * 8;
        boff[t] = LDS_SLOT(wn + t * 16 + fr, fq) * 8;
    }

    f32x4 acc[4][4];
#pragma unroll
    for (int i = 0; i < 4; ++i)
#pragma unroll
        for (int j = 0; j < 4; ++j) acc[i][j] = (f32x4){0.f, 0.f, 0.f, 0.f};

    for (int k0 = 0; k0 < K; k0 += 32) {
        gload_lds16(gA0 + k0, lA0);
        gload_lds16(gA1 + k0, lA1);
        gload_lds16(gB0 + k0, lB0);
        gload_lds16(gB1 + k0, lB1);
        __syncthreads();

        bf16x8 af[4], bf[4];
#pragma unroll
        for (int t = 0; t < 4; ++t) af[t] = *(const bf16x8*)&As[aoff[t]];
#pragma unroll
        for (int t = 0; t < 4; ++t) bf[t] = *(const bf16x8*)&Bs[boff[t]];
#pragma unroll
        for (int i = 0; i < 4; ++i)
#pragma unroll
            for (int j = 0; j < 4; ++j)
                acc[i][j] = __builtin_amdgcn_mfma_f32_16x16x32_bf16(
                    af[i], bf[j], acc[i][j], 0, 0, 0);
        __syncthreads();
    }

    const float qscale = 0.08838834764831845f;
#pragma unroll
    for (int tj = 0; tj < 4; ++tj) {
        const int n = bn + wn + tj * 16 + fr;
        const float bv = bias[n];
#pragma unroll
        for (int ti = 0; ti < 4; ++ti) {
            const int m0 = bm + wm + ti * 16 + fq * 4;
            f32x4 a = acc[ti][tj];
            if (n < D) {
#pragma unroll
                for (int r = 0; r < 4; ++r)
                    Qb[(size_t)(m0 + r) * D + n] = f2bf((a[r] + bv) * qscale);
            } else if (n < 2 * D) {
#pragma unroll
                for (int r = 0; r < 4; ++r)
                    Kb[(size_t)(m0 + r) * D + (n - D)] = f2bf(a[r] + bv);
            } else {
                const int h = (n - 2 * D) >> 7;
                const int dh = (n - 2 * D) & 127;
                const int bb = m0 >> 9;
                const int t = m0 & 511;
                ushort4 pk;
                pk.x = f2bf(a[0] + bv); pk.y = f2bf(a[1] + bv);
                pk.z = f2bf(a[2] + bv); pk.w = f2bf(a[3] + bv);
                *(ushort4*)&Vt[((size_t)(bb * H + h) * DH + dh) * TL + t] = pk;
            }
        }
    }
}

// ---------------- MFMA flash attention -------------------------------------
// grid (TL/64, B*H), 256 thr / 4 waves; wave w owns queries [w*16, w*16+16).
// Q/K rows: DH=128 bf16 = 16 chunks of 16B -> pitch 16, swizzle XOR low 3 bits.
// Vt rows: 64 t = 8 chunks -> pitch 8.
#define LSW16(r, g) ((((r) << 4) + ((g) ^ ((r) & 7))) << 3)
#define LSW8(r, g) ((((r) << 3) + ((g) ^ ((r) & 7))) << 3)

__global__ __launch_bounds__(256, 2) void attn_mfma(
    const ushort_t* __restrict__ Qb, const ushort_t* __restrict__ Kb,
    const ushort_t* __restrict__ Vt, ushort_t* __restrict__ Ab) {
    __shared__ ushort_t Qs[64 * 128];   // 64 q-rows x 16 chunks
    __shared__ ushort_t Ks[64 * 128];   // 64 k-rows x 16 chunks
    __shared__ ushort_t Vts[128 * 64];  // 128 dh-rows x 8 chunks
    __shared__ ushort_t Ps[64 * 72];

    const int q0 = blockIdx.x * 64;
    const int bh = blockIdx.y;
    const int b = bh >> 3;
    const int h = bh & 7;
    const int tid = threadIdx.x;
    const int lane = tid & 63;
    const int w = tid >> 6;
    const int fr = lane & 15;
    const int fq = lane >> 4;

    const float slope = exp2f(-(float)(h + 1));

    // ---- stage Q once: 64 rows x 16 chunks = 1024 chunks ----
#pragma unroll
    for (int kk = 0; kk < 4; ++kk) {
        int s = tid + kk * 256;
        int r = s >> 4, gp = s & 15, gl = gp ^ (r & 7);
        gload_lds16(Qb + (size_t)(b * TL + q0 + r) * D + h * DH + gl * 8,
                    &Qs[s * 8]);
    }

    f32x4 o8[8];
    float m_i[4], l_i[4];
#pragma unroll
    for (int nt = 0; nt < 8; ++nt) o8[nt] = (f32x4){0.f, 0.f, 0.f, 0.f};
#pragma unroll
    for (int r = 0; r < 4; ++r) { m_i[r] = -1e30f; l_i[r] = 0.f; }

    for (int kt = 0; kt < TL / 64; ++kt) {
        __syncthreads();  // prev PV reads done; also drains Q staging (vmcnt)
        // ---- stage K tile: 1024 chunks ----
#pragma unroll
        for (int kk = 0; kk < 4; ++kk) {
            int s = tid + kk * 256;
            int r = s >> 4, gp = s & 15, gl = gp ^ (r & 7);
            gload_lds16(Kb + (size_t)(b * TL + kt * 64 + r) * D + h * DH + gl * 8,
                        &Ks[s * 8]);
        }
        // ---- stage Vt tile: 128 rows x 8 chunks = 1024 chunks ----
#pragma unroll
        for (int kk = 0; kk < 4; ++kk) {
            int s = tid + kk * 256;
            int r = s >> 3, gp = s & 7, gl = gp ^ (r & 7);
            gload_lds16(Vt + ((size_t)bh * DH + r) * TL + kt * 64 + gl * 8,
                        &Vts[s * 8]);
        }
        __syncthreads();

        // ---- S = Q K^T ----
        f32x4 sacc[4];
#pragma unroll
        for (int jt = 0; jt < 4; ++jt) sacc[jt] = (f32x4){0.f, 0.f, 0.f, 0.f};
#pragma unroll
        for (int s4 = 0; s4 < 4; ++s4) {
            bf16x8 aq = *(const bf16x8*)&Qs[LSW16(w * 16 + fr, s4 * 4 + fq)];
#pragma unroll
            for (int jt = 0; jt < 4; ++jt) {
                bf16x8 kb = *(const bf16x8*)&Ks[LSW16(jt * 16 + fr, s4 * 4 + fq)];
                sacc[jt] = __builtin_amdgcn_mfma_f32_16x16x32_bf16(
                    aq, kb, sacc[jt], 0, 0, 0);
            }
        }

        // ---- online softmax (C layout: row = fq*4+r, col = jt*16+fr) ----
        const int iq = q0 + w * 16 + fq * 4;
        const int jk = kt * 64 + fr;
        float al[4];
#pragma unroll
        for (int r = 0; r < 4; ++r) {
            float sv[4];
#pragma unroll
            for (int jt = 0; jt < 4; ++jt)
                sv[jt] = sacc[jt][r] -
                         slope * fabsf((float)(iq + r - jk - jt * 16));
            float mx = fmaxf(fmaxf(sv[0], sv[1]), fmaxf(sv[2], sv[3]));
            mx = fmaxf(mx, __shfl_xor(mx, 1));
            mx = fmaxf(mx, __shfl_xor(mx, 2));
            mx = fmaxf(mx, __shfl_xor(mx, 4));
            mx = fmaxf(mx, __shfl_xor(mx, 8));
            float mnew = fmaxf(m_i[r], mx);
            al[r] = __expf(m_i[r] - mnew);
            float rs = 0.f;
#pragma unroll
            for (int jt = 0; jt < 4; ++jt) {
                sv[jt] = __expf(sv[jt] - mnew);
                rs += sv[jt];
            }
            rs += __shfl_xor(rs, 1);
            rs += __shfl_xor(rs, 2);
            rs += __shfl_xor(rs, 4);
            rs += __shfl_xor(rs, 8);
            l_i[r] = l_i[r] * al[r] + rs;
            m_i[r] = mnew;
            const int prow = w * 16 + fq * 4 + r;
#pragma unroll
            for (int jt = 0; jt < 4; ++jt)
                Ps[prow * 72 + jt * 16 + fr] = f2bf(sv[jt]);
        }
#pragma unroll
        for (int nt = 0; nt < 8; ++nt)
#pragma unroll
            for (int r = 0; r < 4; ++r) o8[nt][r] *= al[r];

        // ---- O += P V  (Ps rows are wave-private; no barrier needed) ----
#pragma unroll
        for (int s2 = 0; s2 < 2; ++s2) {
            bf16x8 pa = *(const bf16x8*)&Ps[(w * 16 + fr) * 72 + s2 * 32 + fq * 8];
#pragma unroll
            for (int nt = 0; nt < 8; ++nt) {
                bf16x8 vb = *(const bf16x8*)&Vts[LSW8(nt * 16 + fr, s2 * 4 + fq)];
                o8[nt] = __builtin_amdgcn_mfma_f32_16x16x32_bf16(
                    pa, vb, o8[nt], 0, 0, 0);
            }
        }
    }

    // ---- write O (bf16) ----
#pragma unroll
    for (int r = 0; r < 4; ++r) {
        float inv = 1.f / l_i[r];
        const size_t base = (size_t)(b * TL + q0 + w * 16 + fq * 4 + r) * D + h * DH;
#pragma unroll
        for (int nt = 0; nt < 8; ++nt)
            Ab[base + nt * 16 + fr] = f2bf(o8[nt][r] * inv);
    }
}

// ---------------- fused residual + LayerNorm (+ bf16 copy out) -------------
__global__ __launch_bounds__(256) void add_ln(const float* __restrict__ x,
                                              const float* __restrict__ y,
                                              const float* __restrict__ g,
                                              const float* __restrict__ bta,
                                              float* __restrict__ out,
                                              ushort_t* __restrict__ outb) {
    __shared__ float red[4];
    const int row = blockIdx.x;
    const int tid = threadIdx.x;
    const size_t base = (size_t)row * D + tid * 4;

    float4 xv = *(const float4*)(x + base);
    float4 yv = *(const float4*)(y + base);
    float v[4] = {xv.x + yv.x, xv.y + yv.y, xv.z + yv.z, xv.w + yv.w};

    float s = v[0] + v[1] + v[2] + v[3];
    for (int off = 32; off; off >>= 1) s += __shfl_down(s, off);
    if ((tid & 63) == 0) red[tid >> 6] = s;
    __syncthreads();
    const float mean = (red[0] + red[1] + red[2] + red[3]) * (1.f / (float)D);
    __syncthreads();

    float d0 = v[0] - mean, d1 = v[1] - mean, d2 = v[2] - mean, d3 = v[3] - mean;
    float sq = d0 * d0 + d1 * d1 + d2 * d2 + d3 * d3;
    for (int off = 32; off; off >>= 1) sq += __shfl_down(sq, off);
    if ((tid & 63) == 0) red[tid >> 6] = sq;
    __syncthreads();
    const float var = (red[0] + red[1] + red[2] + red[3]) * (1.f / (float)D);
    const float inv = rsqrtf(var + 1e-5f);

    float4 gv = *(const float4*)(g + tid * 4);
    float4 bv = *(const float4*)(bta + tid * 4);
    float4 o;
    o.x = d0 * inv * gv.x + bv.x;
    o.y = d1 * inv * gv.y + bv.y;
    o.z = d2 * inv * gv.z + bv.z;
    o.w = d3 * inv * gv.w + bv.w;
    *(float4*)(out + base) = o;
    ushort4 ob;
    ob.x = f2bf(o.x); ob.y = f2bf(o.y); ob.z = f2bf(o.z); ob.w = f2bf(o.w);
    *(ushort4*)(outb + base) = ob;
}

// ---------------- launcher -------------------------------------------------
extern "C" void kernel_launch(void* const* d_in, const int* in_sizes, int n_in,
                              void* d_out, int out_size, void* d_ws, size_t ws_size,
                              hipStream_t stream) {
    const float* x_in   = (const float*)d_in[0];
    const float* pre_w  = (const float*)d_in[1];
    const float* pre_b  = (const float*)d_in[2];
    const float* in_w   = (const float*)d_in[3];
    const float* in_b   = (const float*)d_in[4];
    const float* out_w  = (const float*)d_in[5];
    const float* out_b  = (const float*)d_in[6];
    const float* ln1_g  = (const float*)d_in[7];
    const float* ln1_b  = (const float*)d_in[8];
    const float* ff1_w  = (const float*)d_in[9];
    const float* ff1_b  = (const float*)d_in[10];
    const float* ff2_w  = (const float*)d_in[11];
    const float* ff2_b  = (const float*)d_in[12];
    const float* ln2_g  = (const float*)d_in[13];
    const float* ln2_b  = (const float*)d_in[14];
    const float* post_w = (const float*)d_in[15];
    const float* post_b = (const float*)d_in[16];

    float* X = (float*)d_ws;
    float* Y = X + (size_t)M_ROWS * D;
    ushort_t* Xb   = (ushort_t*)(Y + (size_t)M_ROWS * D);
    ushort_t* Ab   = Xb + (size_t)M_ROWS * D;
    ushort_t* Qb   = Ab + (size_t)M_ROWS * D;
    ushort_t* Kb   = Qb + (size_t)M_ROWS * D;
    ushort_t* Vt   = Kb + (size_t)M_ROWS * D;
    ushort_t* xinb = Vt + (size_t)M_ROWS * D;
    ushort_t* pwb  = xinb + (size_t)M_ROWS * 512;
    ushort_t* iwb  = pwb + (size_t)D * 512;
    ushort_t* owb  = iwb + (size_t)NL * 3 * D * D;
    ushort_t* f1wb = owb + (size_t)NL * D * D;
    ushort_t* f2wb = f1wb + (size_t)NL * DFF * D;
    ushort_t* powb = f2wb + (size_t)NL * D * DFF;

    const dim3 blk(256);
    const int cg = 1024;

    cvt_bf16<<<cg, blk, 0, stream>>>(x_in, xinb, M_ROWS * 512);
    cvt_bf16<<<cg, blk, 0, stream>>>(pre_w, pwb, D * 512);
    cvt_bf16<<<cg, blk, 0, stream>>>(in_w, iwb, NL * 3 * D * D);
    cvt_bf16<<<cg, blk, 0, stream>>>(out_w, owb, NL * D * D);
    cvt_bf16<<<cg, blk, 0, stream>>>(ff1_w, f1wb, NL * DFF * D);
    cvt_bf16<<<cg, blk, 0, stream>>>(ff2_w, f2wb, NL * D * DFF);
    cvt_bf16<<<cg, blk, 0, stream>>>(post_w, powb, D * D);

    const dim3 gD(D / 128, M_ROWS / 128);
    const dim3 gQKV(3 * D / 128, M_ROWS / 128);

    gemm_bf16<<<gD, blk, 0, stream>>>(xinb, pwb, pre_b, X, Xb,
                                      M_ROWS, D, 512, 0);

    for (int l = 0; l < NL; ++l) {
        gemm_qkv<<<gQKV, blk, 0, stream>>>(Xb, iwb + (size_t)l * 3 * D * D,
                                           in_b + (size_t)l * 3 * D,
                                           Qb, Kb, Vt, D);
        attn_mfma<<<dim3(TL / 64, B * H), blk, 0, stream>>>(Qb, Kb, Vt, Ab);
        gemm_bf16<<<gD, blk, 0, stream>>>(Ab, owb + (size_t)l * D * D,
                                          out_b + (size_t)l * D, Y, nullptr,
                                          M_ROWS, D, D, 0);
        add_ln<<<dim3(M_ROWS), blk, 0, stream>>>(X, Y, ln1_g + (size_t)l * D,
                                                 ln1_b + (size_t)l * D, X, Xb);
        gemm_bf16<<<gD, blk, 0, stream>>>(Xb, f1wb + (size_t)l * DFF * D,
                                          ff1_b + (size_t)l * DFF, nullptr, Ab,
                                          M_ROWS, DFF, D, 1);
        gemm_bf16<<<gD, blk, 0, stream>>>(Ab, f2wb + (size_t)l * D * DFF,
                                          ff2_b + (size_t)l * D, Y, nullptr,
                                          M_ROWS, D, DFF, 0);
        add_ln<<<dim3(M_ROWS), blk, 0, stream>>>(X, Y, ln2_g + (size_t)l * D,
                                                 ln2_b + (size_t)l * D, X, Xb);
    }

    gemm_bf16<<<gD, blk, 0, stream>>>(Xb, powb, post_b, (float*)d_out, nullptr,
                                      M_ROWS, D, D, 0);
}

// Round 7
// 1215.074 us; speedup vs baseline: 13.1647x; 1.1450x over previous
//
#include <hip/hip_runtime.h>
#include <hip/hip_bf16.h>

// ---------------- problem constants ----------------
#define B 8
#define TL 512
#define M_ROWS 4096
#define D 1024
#define DFF 1024
#define H 8
#define DH 128
#define NL 6

typedef unsigned short ushort_t;
typedef unsigned int uint_t;
typedef short bf16x8 __attribute__((ext_vector_type(8)));
typedef float f32x4 __attribute__((ext_vector_type(4)));

__device__ __forceinline__ ushort_t f2bf(float f) {
    uint_t u = __float_as_uint(f);
    u += 0x7FFFu + ((u >> 16) & 1u);
    return (ushort_t)(u >> 16);
}
__device__ __forceinline__ float gelu_exact(float x) {
    return 0.5f * x * (1.0f + erff(x * 0.70710678118654752f));
}
__device__ __forceinline__ void gload_lds16(const ushort_t* g, ushort_t* l) {
    __builtin_amdgcn_global_load_lds(
        (const __attribute__((address_space(1))) void*)g,
        (__attribute__((address_space(3))) void*)l, 16, 0, 0);
}

// ---------------- fused f32 -> bf16 conversion (7 segments, 1 launch) ------
struct CvtArgs {
    const float* s[7];
    ushort_t* d[7];
    int n[7];  // element counts, multiples of 4
};

__global__ __launch_bounds__(256) void cvt_all(CvtArgs a) {
    const int stride = gridDim.x * blockDim.x;
    const int t0 = blockIdx.x * blockDim.x + threadIdx.x;
#pragma unroll
    for (int seg = 0; seg < 7; ++seg) {
        const float* s = a.s[seg];
        ushort_t* d = a.d[seg];
        const int nq = a.n[seg] >> 2;
        for (int i = t0; i < nq; i += stride) {
            float4 v = *(const float4*)(s + (size_t)i * 4);
            ushort4 o;
            o.x = f2bf(v.x); o.y = f2bf(v.y); o.z = f2bf(v.z); o.w = f2bf(v.w);
            *(ushort4*)(d + (size_t)i * 4) = o;
        }
    }
}

#define LDS_SLOT(r, g) (((r) << 2) + ((g) ^ (((r) >> 1) & 3)))

// ---------------- N=1024 GEMM: 128Mx64N tile, BK=32 ------------------------
// grid (N/64, M/128) = 512 blocks -> 2 blocks/CU -> 2 waves/SIMD (latency
// hiding; the 128x128 version is grid-limited to 1 wave/SIMD for N=1024).
// 4 waves, each 64Mx32N = 4x2 MFMA tiles. Staging: A 512 chunks (2/thread),
// B 256 chunks (1/thread), same baked XOR swizzle (0 conflicts measured R6).
__global__ __launch_bounds__(256) void gemm_n64(
    const ushort_t* __restrict__ A, const ushort_t* __restrict__ W,
    const float* __restrict__ bias, float* __restrict__ Cf,
    ushort_t* __restrict__ Cb, int M, int N, int K, int do_gelu) {
    __shared__ ushort_t As[128 * 32];
    __shared__ ushort_t Bs[64 * 32];

    const int tid = threadIdx.x;
    const int lane = tid & 63;
    const int w = tid >> 6;
    const int wm = (w & 2) * 32;   // 0 or 64
    const int wn = (w & 1) * 32;   // 0 or 32
    const int bm = blockIdx.y * 128;
    const int bn = blockIdx.x * 64;

    const int sA0 = tid, sA1 = tid + 256, sB = tid;
    const int rA0 = sA0 >> 2, gA0c = (sA0 & 3) ^ ((rA0 >> 1) & 3);
    const int rA1 = sA1 >> 2, gA1c = (sA1 & 3) ^ ((rA1 >> 1) & 3);
    const int rB = sB >> 2, gBc = (sB & 3) ^ ((rB >> 1) & 3);
    const ushort_t* gA0 = A + (size_t)(bm + rA0) * K + gA0c * 8;
    const ushort_t* gA1 = A + (size_t)(bm + rA1) * K + gA1c * 8;
    const ushort_t* gB0 = W + (size_t)(bn + rB) * K + gBc * 8;
    ushort_t* lA0 = &As[sA0 * 8];
    ushort_t* lA1 = &As[sA1 * 8];
    ushort_t* lB0 = &Bs[sB * 8];

    const int fr = lane & 15;
    const int fq = lane >> 4;
    int aoff[4], boff[2];
#pragma unroll
    for (int t = 0; t < 4; ++t) aoff[t] = LDS_SLOT(wm + t * 16 + fr, fq) * 8;
#pragma unroll
    for (int t = 0; t < 2; ++t) boff[t] = LDS_SLOT(wn + t * 16 + fr, fq) * 8;

    f32x4 acc[4][2];
#pragma unroll
    for (int i = 0; i < 4; ++i)
#pragma unroll
        for (int j = 0; j < 2; ++j) acc[i][j] = (f32x4){0.f, 0.f, 0.f, 0.f};

    for (int k0 = 0; k0 < K; k0 += 32) {
        gload_lds16(gA0 + k0, lA0);
        gload_lds16(gA1 + k0, lA1);
        gload_lds16(gB0 + k0, lB0);
        __syncthreads();

        bf16x8 af[4], bf[2];
#pragma unroll
        for (int t = 0; t < 4; ++t) af[t] = *(const bf16x8*)&As[aoff[t]];
#pragma unroll
        for (int t = 0; t < 2; ++t) bf[t] = *(const bf16x8*)&Bs[boff[t]];
#pragma unroll
        for (int i = 0; i < 4; ++i)
#pragma unroll
            for (int j = 0; j < 2; ++j)
                acc[i][j] = __builtin_amdgcn_mfma_f32_16x16x32_bf16(
                    af[i], bf[j], acc[i][j], 0, 0, 0);
        __syncthreads();
    }

#pragma unroll
    for (int tj = 0; tj < 2; ++tj) {
        const int n = bn + wn + tj * 16 + fr;
        const float bv = bias[n];
#pragma unroll
        for (int ti = 0; ti < 4; ++ti) {
            const int m0 = bm + wm + ti * 16 + fq * 4;
            f32x4 a = acc[ti][tj];
#pragma unroll
            for (int r = 0; r < 4; ++r) {
                float v = a[r] + bv;
                if (do_gelu) v = gelu_exact(v);
                const size_t off = (size_t)(m0 + r) * N + n;
                if (Cf) Cf[off] = v;
                if (Cb) Cb[off] = f2bf(v);
            }
        }
    }
}

// ---------------- QKV GEMM: 128x128, bf16 out, V transposed ----------------
__global__ __launch_bounds__(256) void gemm_qkv(
    const ushort_t* __restrict__ A, const ushort_t* __restrict__ W,
    const float* __restrict__ bias, ushort_t* __restrict__ Qb,
    ushort_t* __restrict__ Kb, ushort_t* __restrict__ Vt, int K) {
    __shared__ ushort_t As[128 * 32];
    __shared__ ushort_t Bs[128 * 32];

    const int tid = threadIdx.x;
    const int lane = tid & 63;
    const int w = tid >> 6;
    const int wm = (w >> 1) * 64;
    const int wn = (w & 1) * 64;
    const int bm = blockIdx.y * 128;
    const int bn = blockIdx.x * 128;

    const int s0 = tid, s1 = tid + 256;
    const int r0 = s0 >> 2, g0 = (s0 & 3) ^ ((r0 >> 1) & 3);
    const int r1 = s1 >> 2, g1 = (s1 & 3) ^ ((r1 >> 1) & 3);
    const ushort_t* gA0 = A + (size_t)(bm + r0) * K + g0 * 8;
    const ushort_t* gA1 = A + (size_t)(bm + r1) * K + g1 * 8;
    const ushort_t* gB0 = W + (size_t)(bn + r0) * K + g0 * 8;
    const ushort_t* gB1 = W + (size_t)(bn + r1) * K + g1 * 8;
    ushort_t* lA0 = &As[s0 * 8];
    ushort_t* lA1 = &As[s1 * 8];
    ushort_t* lB0 = &Bs[s0 * 8];
    ushort_t* lB1 = &Bs[s1 * 8];

    const int fr = lane & 15;
    const int fq = lane >> 4;
    int aoff[4], boff[4];
#pragma unroll
    for (int t = 0; t < 4; ++t) {
        aoff[t] = LDS_SLOT(wm + t * 16 + fr, fq) * 8;
        boff[t] = LDS_SLOT(wn + t * 16 + fr, fq) * 8;
    }

    f32x4 acc[4][4];
#pragma unroll
    for (int i = 0; i < 4; ++i)
#pragma unroll
        for (int j = 0; j < 4; ++j) acc[i][j] = (f32x4){0.f, 0.f, 0.f, 0.f};

    for (int k0 = 0; k0 < K; k0 += 32) {
        gload_lds16(gA0 + k0, lA0);
        gload_lds16(gA1 + k0, lA1);
        gload_lds16(gB0 + k0, lB0);
        gload_lds16(gB1 + k0, lB1);
        __syncthreads();

        bf16x8 af[4], bf[4];
#pragma unroll
        for (int t = 0; t < 4; ++t) af[t] = *(const bf16x8*)&As[aoff[t]];
#pragma unroll
        for (int t = 0; t < 4; ++t) bf[t] = *(const bf16x8*)&Bs[boff[t]];
#pragma unroll
        for (int i = 0; i < 4; ++i)
#pragma unroll
            for (int j = 0; j < 4; ++j)
                acc[i][j] = __builtin_amdgcn_mfma_f32_16x16x32_bf16(
                    af[i], bf[j], acc[i][j], 0, 0, 0);
        __syncthreads();
    }

    const float qscale = 0.08838834764831845f;
#pragma unroll
    for (int tj = 0; tj < 4; ++tj) {
        const int n = bn + wn + tj * 16 + fr;
        const float bv = bias[n];
#pragma unroll
        for (int ti = 0; ti < 4; ++ti) {
            const int m0 = bm + wm + ti * 16 + fq * 4;
            f32x4 a = acc[ti][tj];
            if (n < D) {
#pragma unroll
                for (int r = 0; r < 4; ++r)
                    Qb[(size_t)(m0 + r) * D + n] = f2bf((a[r] + bv) * qscale);
            } else if (n < 2 * D) {
#pragma unroll
                for (int r = 0; r < 4; ++r)
                    Kb[(size_t)(m0 + r) * D + (n - D)] = f2bf(a[r] + bv);
            } else {
                const int h = (n - 2 * D) >> 7;
                const int dh = (n - 2 * D) & 127;
                const int bb = m0 >> 9;
                const int t = m0 & 511;
                ushort4 pk;
                pk.x = f2bf(a[0] + bv); pk.y = f2bf(a[1] + bv);
                pk.z = f2bf(a[2] + bv); pk.w = f2bf(a[3] + bv);
                *(ushort4*)&Vt[((size_t)(bb * H + h) * DH + dh) * TL + t] = pk;
            }
        }
    }
}

// ---------------- MFMA flash attention -------------------------------------
#define LSW16(r, g) ((((r) << 4) + ((g) ^ ((r) & 7))) << 3)
#define LSW8(r, g) ((((r) << 3) + ((g) ^ ((r) & 7))) << 3)

__global__ __launch_bounds__(256, 2) void attn_mfma(
    const ushort_t* __restrict__ Qb, const ushort_t* __restrict__ Kb,
    const ushort_t* __restrict__ Vt, ushort_t* __restrict__ Ab) {
    __shared__ ushort_t Qs[64 * 128];
    __shared__ ushort_t Ks[64 * 128];
    __shared__ ushort_t Vts[128 * 64];
    __shared__ ushort_t Ps[64 * 72];

    const int q0 = blockIdx.x * 64;
    const int bh = blockIdx.y;
    const int b = bh >> 3;
    const int h = bh & 7;
    const int tid = threadIdx.x;
    const int lane = tid & 63;
    const int w = tid >> 6;
    const int fr = lane & 15;
    const int fq = lane >> 4;

    const float slope = exp2f(-(float)(h + 1));

#pragma unroll
    for (int kk = 0; kk < 4; ++kk) {
        int s = tid + kk * 256;
        int r = s >> 4, gp = s & 15, gl = gp ^ (r & 7);
        gload_lds16(Qb + (size_t)(b * TL + q0 + r) * D + h * DH + gl * 8,
                    &Qs[s * 8]);
    }

    f32x4 o8[8];
    float m_i[4], l_i[4];
#pragma unroll
    for (int nt = 0; nt < 8; ++nt) o8[nt] = (f32x4){0.f, 0.f, 0.f, 0.f};
#pragma unroll
    for (int r = 0; r < 4; ++r) { m_i[r] = -1e30f; l_i[r] = 0.f; }

    for (int kt = 0; kt < TL / 64; ++kt) {
        __syncthreads();
#pragma unroll
        for (int kk = 0; kk < 4; ++kk) {
            int s = tid + kk * 256;
            int r = s >> 4, gp = s & 15, gl = gp ^ (r & 7);
            gload_lds16(Kb + (size_t)(b * TL + kt * 64 + r) * D + h * DH + gl * 8,
                        &Ks[s * 8]);
        }
#pragma unroll
        for (int kk = 0; kk < 4; ++kk) {
            int s = tid + kk * 256;
            int r = s >> 3, gp = s & 7, gl = gp ^ (r & 7);
            gload_lds16(Vt + ((size_t)bh * DH + r) * TL + kt * 64 + gl * 8,
                        &Vts[s * 8]);
        }
        __syncthreads();

        f32x4 sacc[4];
#pragma unroll
        for (int jt = 0; jt < 4; ++jt) sacc[jt] = (f32x4){0.f, 0.f, 0.f, 0.f};
#pragma unroll
        for (int s4 = 0; s4 < 4; ++s4) {
            bf16x8 aq = *(const bf16x8*)&Qs[LSW16(w * 16 + fr, s4 * 4 + fq)];
#pragma unroll
            for (int jt = 0; jt < 4; ++jt) {
                bf16x8 kb = *(const bf16x8*)&Ks[LSW16(jt * 16 + fr, s4 * 4 + fq)];
                sacc[jt] = __builtin_amdgcn_mfma_f32_16x16x32_bf16(
                    aq, kb, sacc[jt], 0, 0, 0);
            }
        }

        const int iq = q0 + w * 16 + fq * 4;
        const int jk = kt * 64 + fr;
        float al[4];
#pragma unroll
        for (int r = 0; r < 4; ++r) {
            float sv[4];
#pragma unroll
            for (int jt = 0; jt < 4; ++jt)
                sv[jt] = sacc[jt][r] -
                         slope * fabsf((float)(iq + r - jk - jt * 16));
            float mx = fmaxf(fmaxf(sv[0], sv[1]), fmaxf(sv[2], sv[3]));
            mx = fmaxf(mx, __shfl_xor(mx, 1));
            mx = fmaxf(mx, __shfl_xor(mx, 2));
            mx = fmaxf(mx, __shfl_xor(mx, 4));
            mx = fmaxf(mx, __shfl_xor(mx, 8));
            float mnew = fmaxf(m_i[r], mx);
            al[r] = __expf(m_i[r] - mnew);
            float rs = 0.f;
#pragma unroll
            for (int jt = 0; jt < 4; ++jt) {
                sv[jt] = __expf(sv[jt] - mnew);
                rs += sv[jt];
            }
            rs += __shfl_xor(rs, 1);
            rs += __shfl_xor(rs, 2);
            rs += __shfl_xor(rs, 4);
            rs += __shfl_xor(rs, 8);
            l_i[r] = l_i[r] * al[r] + rs;
            m_i[r] = mnew;
            const int prow = w * 16 + fq * 4 + r;
#pragma unroll
            for (int jt = 0; jt < 4; ++jt)
                Ps[prow * 72 + jt * 16 + fr] = f2bf(sv[jt]);
        }
#pragma unroll
        for (int nt = 0; nt < 8; ++nt)
#pragma unroll
            for (int r = 0; r < 4; ++r) o8[nt][r] *= al[r];

#pragma unroll
        for (int s2 = 0; s2 < 2; ++s2) {
            bf16x8 pa = *(const bf16x8*)&Ps[(w * 16 + fr) * 72 + s2 * 32 + fq * 8];
#pragma unroll
            for (int nt = 0; nt < 8; ++nt) {
                bf16x8 vb = *(const bf16x8*)&Vts[LSW8(nt * 16 + fr, s2 * 4 + fq)];
                o8[nt] = __builtin_amdgcn_mfma_f32_16x16x32_bf16(
                    pa, vb, o8[nt], 0, 0, 0);
            }
        }
    }

#pragma unroll
    for (int r = 0; r < 4; ++r) {
        float inv = 1.f / l_i[r];
        const size_t base = (size_t)(b * TL + q0 + w * 16 + fq * 4 + r) * D + h * DH;
#pragma unroll
        for (int nt = 0; nt < 8; ++nt)
            Ab[base + nt * 16 + fr] = f2bf(o8[nt][r] * inv);
    }
}

// ---------------- fused residual + LayerNorm (+ bf16 copy out) -------------
__global__ __launch_bounds__(256) void add_ln(const float* __restrict__ x,
                                              const float* __restrict__ y,
                                              const float* __restrict__ g,
                                              const float* __restrict__ bta,
                                              float* __restrict__ out,
                                              ushort_t* __restrict__ outb) {
    __shared__ float red[4];
    const int row = blockIdx.x;
    const int tid = threadIdx.x;
    const size_t base = (size_t)row * D + tid * 4;

    float4 xv = *(const float4*)(x + base);
    float4 yv = *(const float4*)(y + base);
    float v[4] = {xv.x + yv.x, xv.y + yv.y, xv.z + yv.z, xv.w + yv.w};

    float s = v[0] + v[1] + v[2] + v[3];
    for (int off = 32; off; off >>= 1) s += __shfl_down(s, off);
    if ((tid & 63) == 0) red[tid >> 6] = s;
    __syncthreads();
    const float mean = (red[0] + red[1] + red[2] + red[3]) * (1.f / (float)D);
    __syncthreads();

    float d0 = v[0] - mean, d1 = v[1] - mean, d2 = v[2] - mean, d3 = v[3] - mean;
    float sq = d0 * d0 + d1 * d1 + d2 * d2 + d3 * d3;
    for (int off = 32; off; off >>= 1) sq += __shfl_down(sq, off);
    if ((tid & 63) == 0) red[tid >> 6] = sq;
    __syncthreads();
    const float var = (red[0] + red[1] + red[2] + red[3]) * (1.f / (float)D);
    const float inv = rsqrtf(var + 1e-5f);

    float4 gv = *(const float4*)(g + tid * 4);
    float4 bv = *(const float4*)(bta + tid * 4);
    float4 o;
    o.x = d0 * inv * gv.x + bv.x;
    o.y = d1 * inv * gv.y + bv.y;
    o.z = d2 * inv * gv.z + bv.z;
    o.w = d3 * inv * gv.w + bv.w;
    *(float4*)(out + base) = o;
    ushort4 ob;
    ob.x = f2bf(o.x); ob.y = f2bf(o.y); ob.z = f2bf(o.z); ob.w = f2bf(o.w);
    *(ushort4*)(outb + base) = ob;
}

// ---------------- launcher -------------------------------------------------
extern "C" void kernel_launch(void* const* d_in, const int* in_sizes, int n_in,
                              void* d_out, int out_size, void* d_ws, size_t ws_size,
                              hipStream_t stream) {
    const float* x_in   = (const float*)d_in[0];
    const float* pre_w  = (const float*)d_in[1];
    const float* pre_b  = (const float*)d_in[2];
    const float* in_w   = (const float*)d_in[3];
    const float* in_b   = (const float*)d_in[4];
    const float* out_w  = (const float*)d_in[5];
    const float* out_b  = (const float*)d_in[6];
    const float* ln1_g  = (const float*)d_in[7];
    const float* ln1_b  = (const float*)d_in[8];
    const float* ff1_w  = (const float*)d_in[9];
    const float* ff1_b  = (const float*)d_in[10];
    const float* ff2_w  = (const float*)d_in[11];
    const float* ff2_b  = (const float*)d_in[12];
    const float* ln2_g  = (const float*)d_in[13];
    const float* ln2_b  = (const float*)d_in[14];
    const float* post_w = (const float*)d_in[15];
    const float* post_b = (const float*)d_in[16];

    float* X = (float*)d_ws;
    float* Y = X + (size_t)M_ROWS * D;
    ushort_t* Xb   = (ushort_t*)(Y + (size_t)M_ROWS * D);
    ushort_t* Ab   = Xb + (size_t)M_ROWS * D;
    ushort_t* Qb   = Ab + (size_t)M_ROWS * D;
    ushort_t* Kb   = Qb + (size_t)M_ROWS * D;
    ushort_t* Vt   = Kb + (size_t)M_ROWS * D;
    ushort_t* xinb = Vt + (size_t)M_ROWS * D;
    ushort_t* pwb  = xinb + (size_t)M_ROWS * 512;
    ushort_t* iwb  = pwb + (size_t)D * 512;
    ushort_t* owb  = iwb + (size_t)NL * 3 * D * D;
    ushort_t* f1wb = owb + (size_t)NL * D * D;
    ushort_t* f2wb = f1wb + (size_t)NL * DFF * D;
    ushort_t* powb = f2wb + (size_t)NL * D * DFF;

    const dim3 blk(256);

    CvtArgs ca;
    ca.s[0] = x_in;   ca.d[0] = xinb; ca.n[0] = M_ROWS * 512;
    ca.s[1] = pre_w;  ca.d[1] = pwb;  ca.n[1] = D * 512;
    ca.s[2] = in_w;   ca.d[2] = iwb;  ca.n[2] = NL * 3 * D * D;
    ca.s[3] = out_w;  ca.d[3] = owb;  ca.n[3] = NL * D * D;
    ca.s[4] = ff1_w;  ca.d[4] = f1wb; ca.n[4] = NL * DFF * D;
    ca.s[5] = ff2_w;  ca.d[5] = f2wb; ca.n[5] = NL * D * DFF;
    ca.s[6] = post_w; ca.d[6] = powb; ca.n[6] = D * D;
    cvt_all<<<1024, blk, 0, stream>>>(ca);

    const dim3 gN64(D / 64, M_ROWS / 128);          // 16 x 32 = 512 blocks
    const dim3 gQKV(3 * D / 128, M_ROWS / 128);     // 24 x 32 = 768 blocks

    gemm_n64<<<gN64, blk, 0, stream>>>(xinb, pwb, pre_b, X, Xb,
                                       M_ROWS, D, 512, 0);

    for (int l = 0; l < NL; ++l) {
        gemm_qkv<<<gQKV, blk, 0, stream>>>(Xb, iwb + (size_t)l * 3 * D * D,
                                           in_b + (size_t)l * 3 * D,
                                           Qb, Kb, Vt, D);
        attn_mfma<<<dim3(TL / 64, B * H), blk, 0, stream>>>(Qb, Kb, Vt, Ab);
        gemm_n64<<<gN64, blk, 0, stream>>>(Ab, owb + (size_t)l * D * D,
                                           out_b + (size_t)l * D, Y, nullptr,
                                           M_ROWS, D, D, 0);
        add_ln<<<dim3(M_ROWS), blk, 0, stream>>>(X, Y, ln1_g + (size_t)l * D,
                                                 ln1_b + (size_t)l * D, X, Xb);
        gemm_n64<<<gN64, blk, 0, stream>>>(Xb, f1wb + (size_t)l * DFF * D,
                                           ff1_b + (size_t)l * DFF, nullptr, Ab,
                                           M_ROWS, DFF, D, 1);
        gemm_n64<<<gN64, blk, 0, stream>>>(Ab, f2wb + (size_t)l * D * DFF,
                                           ff2_b + (size_t)l * D, Y, nullptr,
                                           M_ROWS, D, DFF, 0);
        add_ln<<<dim3(M_ROWS), blk, 0, stream>>>(X, Y, ln2_g + (size_t)l * D,
                                                 ln2_b + (size_t)l * D, X, Xb);
    }

    gemm_n64<<<gN64, blk, 0, stream>>>(Xb, powb, post_b, (float*)d_out, nullptr,
                                       M_ROWS, D, D, 0);
}

// Round 8
// 1147.877 us; speedup vs baseline: 13.9353x; 1.0585x over previous
//
#include <hip/hip_runtime.h>
#include <hip/hip_bf16.h>

// ---------------- problem constants ----------------
#define B 8
#define TL 512
#define M_ROWS 4096
#define D 1024
#define DFF 1024
#define H 8
#define DH 128
#define NL 6

typedef unsigned short ushort_t;
typedef unsigned int uint_t;
typedef short bf16x8 __attribute__((ext_vector_type(8)));
typedef float f32x4 __attribute__((ext_vector_type(4)));

__device__ __forceinline__ ushort_t f2bf(float f) {
    uint_t u = __float_as_uint(f);
    u += 0x7FFFu + ((u >> 16) & 1u);
    return (ushort_t)(u >> 16);
}
__device__ __forceinline__ float gelu_exact(float x) {
    return 0.5f * x * (1.0f + erff(x * 0.70710678118654752f));
}
__device__ __forceinline__ void gload_lds16(const ushort_t* g, ushort_t* l) {
    __builtin_amdgcn_global_load_lds(
        (const __attribute__((address_space(1))) void*)g,
        (__attribute__((address_space(3))) void*)l, 16, 0, 0);
}

// ---------------- f32 -> bf16 conversion, block-partitioned ----------------
struct CvtArgs {
    const float* s[7];
    ushort_t* d[7];
    int nq[7];      // float4-chunk counts
    int bstart[8];  // block ranges per segment
};

__global__ __launch_bounds__(256) void cvt_all(CvtArgs a) {
    const int bid = blockIdx.x;
#pragma unroll
    for (int seg = 0; seg < 7; ++seg) {
        const int b0 = a.bstart[seg], b1 = a.bstart[seg + 1];
        if (bid < b0 || bid >= b1) continue;
        const int stride = (b1 - b0) * 256;
        const float* s = a.s[seg];
        ushort_t* d = a.d[seg];
        const int nq = a.nq[seg];
        for (int i = (bid - b0) * 256 + threadIdx.x; i < nq; i += stride) {
            float4 v = *(const float4*)(s + (size_t)i * 4);
            ushort4 o;
            o.x = f2bf(v.x); o.y = f2bf(v.y); o.z = f2bf(v.z); o.w = f2bf(v.w);
            *(ushort4*)(d + (size_t)i * 4) = o;
        }
    }
}

// LDS row = 8 chunks of 16B (BK=64 bf16); XOR swizzle baked into staging.
#define LSLOT64(r, c) (((r) * 8 + ((c) ^ ((r) & 7))) * 8)

// ---------------- N=1024 GEMM: 128Mx64N tile, BK=64 ------------------------
// 512 blocks -> 2 blocks/CU; 4 waves x (4x2) MFMA tiles x 2 k-steps/iter.
__global__ __launch_bounds__(256) void gemm_n64(
    const ushort_t* __restrict__ A, const ushort_t* __restrict__ W,
    const float* __restrict__ bias, float* __restrict__ Cf,
    ushort_t* __restrict__ Cb, int M, int N, int K, int do_gelu) {
    __shared__ ushort_t As[128 * 64];  // 16 KB
    __shared__ ushort_t Bs[64 * 64];   // 8 KB

    const int tid = threadIdx.x;
    const int lane = tid & 63;
    const int w = tid >> 6;
    const int wm = (w & 2) * 32;
    const int wn = (w & 1) * 32;
    const int bm = blockIdx.y * 128;
    const int bn = blockIdx.x * 64;

    const ushort_t* gA[4];
    ushort_t* lA[4];
#pragma unroll
    for (int t = 0; t < 4; ++t) {
        int s = tid + t * 256;
        int r = s >> 3, gl = (s & 7) ^ (r & 7);
        gA[t] = A + (size_t)(bm + r) * K + gl * 8;
        lA[t] = &As[s * 8];
    }
    const ushort_t* gB[2];
    ushort_t* lB[2];
#pragma unroll
    for (int t = 0; t < 2; ++t) {
        int s = tid + t * 256;
        int r = s >> 3, gl = (s & 7) ^ (r & 7);
        gB[t] = W + (size_t)(bn + r) * K + gl * 8;
        lB[t] = &Bs[s * 8];
    }

    const int fr = lane & 15;
    const int fq = lane >> 4;
    int aoff[4][2], boff[2][2];
#pragma unroll
    for (int t = 0; t < 4; ++t)
#pragma unroll
        for (int s = 0; s < 2; ++s)
            aoff[t][s] = LSLOT64(wm + t * 16 + fr, s * 4 + fq);
#pragma unroll
    for (int t = 0; t < 2; ++t)
#pragma unroll
        for (int s = 0; s < 2; ++s)
            boff[t][s] = LSLOT64(wn + t * 16 + fr, s * 4 + fq);

    f32x4 acc[4][2];
#pragma unroll
    for (int i = 0; i < 4; ++i)
#pragma unroll
        for (int j = 0; j < 2; ++j) acc[i][j] = (f32x4){0.f, 0.f, 0.f, 0.f};

    for (int k0 = 0; k0 < K; k0 += 64) {
#pragma unroll
        for (int t = 0; t < 4; ++t) gload_lds16(gA[t] + k0, lA[t]);
#pragma unroll
        for (int t = 0; t < 2; ++t) gload_lds16(gB[t] + k0, lB[t]);
        __syncthreads();

#pragma unroll
        for (int s = 0; s < 2; ++s) {
            bf16x8 af[4], bf[2];
#pragma unroll
            for (int t = 0; t < 4; ++t) af[t] = *(const bf16x8*)&As[aoff[t][s]];
#pragma unroll
            for (int t = 0; t < 2; ++t) bf[t] = *(const bf16x8*)&Bs[boff[t][s]];
#pragma unroll
            for (int i = 0; i < 4; ++i)
#pragma unroll
                for (int j = 0; j < 2; ++j)
                    acc[i][j] = __builtin_amdgcn_mfma_f32_16x16x32_bf16(
                        af[i], bf[j], acc[i][j], 0, 0, 0);
        }
        __syncthreads();
    }

#pragma unroll
    for (int tj = 0; tj < 2; ++tj) {
        const int n = bn + wn + tj * 16 + fr;
        const float bv = bias[n];
#pragma unroll
        for (int ti = 0; ti < 4; ++ti) {
            const int m0 = bm + wm + ti * 16 + fq * 4;
            f32x4 a = acc[ti][tj];
#pragma unroll
            for (int r = 0; r < 4; ++r) {
                float v = a[r] + bv;
                if (do_gelu) v = gelu_exact(v);
                const size_t off = (size_t)(m0 + r) * N + n;
                if (Cf) Cf[off] = v;
                if (Cb) Cb[off] = f2bf(v);
            }
        }
    }
}

// ---------------- QKV GEMM: 128x128 tile, BK=64, V transposed --------------
__global__ __launch_bounds__(256) void gemm_qkv(
    const ushort_t* __restrict__ A, const ushort_t* __restrict__ W,
    const float* __restrict__ bias, ushort_t* __restrict__ Qb,
    ushort_t* __restrict__ Kb, ushort_t* __restrict__ Vt, int K) {
    __shared__ ushort_t As[128 * 64];  // 16 KB
    __shared__ ushort_t Bs[128 * 64];  // 16 KB

    const int tid = threadIdx.x;
    const int lane = tid & 63;
    const int w = tid >> 6;
    const int wm = (w >> 1) * 64;
    const int wn = (w & 1) * 64;
    const int bm = blockIdx.y * 128;
    const int bn = blockIdx.x * 128;

    const ushort_t* gA[4];
    const ushort_t* gB[4];
    ushort_t* lA[4];
    ushort_t* lB[4];
#pragma unroll
    for (int t = 0; t < 4; ++t) {
        int s = tid + t * 256;
        int r = s >> 3, gl = (s & 7) ^ (r & 7);
        gA[t] = A + (size_t)(bm + r) * K + gl * 8;
        gB[t] = W + (size_t)(bn + r) * K + gl * 8;
        lA[t] = &As[s * 8];
        lB[t] = &Bs[s * 8];
    }

    const int fr = lane & 15;
    const int fq = lane >> 4;
    int aoff[4][2], boff[4][2];
#pragma unroll
    for (int t = 0; t < 4; ++t)
#pragma unroll
        for (int s = 0; s < 2; ++s) {
            aoff[t][s] = LSLOT64(wm + t * 16 + fr, s * 4 + fq);
            boff[t][s] = LSLOT64(wn + t * 16 + fr, s * 4 + fq);
        }

    f32x4 acc[4][4];
#pragma unroll
    for (int i = 0; i < 4; ++i)
#pragma unroll
        for (int j = 0; j < 4; ++j) acc[i][j] = (f32x4){0.f, 0.f, 0.f, 0.f};

    for (int k0 = 0; k0 < K; k0 += 64) {
#pragma unroll
        for (int t = 0; t < 4; ++t) gload_lds16(gA[t] + k0, lA[t]);
#pragma unroll
        for (int t = 0; t < 4; ++t) gload_lds16(gB[t] + k0, lB[t]);
        __syncthreads();

#pragma unroll
        for (int s = 0; s < 2; ++s) {
            bf16x8 af[4], bf[4];
#pragma unroll
            for (int t = 0; t < 4; ++t) af[t] = *(const bf16x8*)&As[aoff[t][s]];
#pragma unroll
            for (int t = 0; t < 4; ++t) bf[t] = *(const bf16x8*)&Bs[boff[t][s]];
#pragma unroll
            for (int i = 0; i < 4; ++i)
#pragma unroll
                for (int j = 0; j < 4; ++j)
                    acc[i][j] = __builtin_amdgcn_mfma_f32_16x16x32_bf16(
                        af[i], bf[j], acc[i][j], 0, 0, 0);
        }
        __syncthreads();
    }

    const float qscale = 0.08838834764831845f;
#pragma unroll
    for (int tj = 0; tj < 4; ++tj) {
        const int n = bn + wn + tj * 16 + fr;
        const float bv = bias[n];
#pragma unroll
        for (int ti = 0; ti < 4; ++ti) {
            const int m0 = bm + wm + ti * 16 + fq * 4;
            f32x4 a = acc[ti][tj];
            if (n < D) {
#pragma unroll
                for (int r = 0; r < 4; ++r)
                    Qb[(size_t)(m0 + r) * D + n] = f2bf((a[r] + bv) * qscale);
            } else if (n < 2 * D) {
#pragma unroll
                for (int r = 0; r < 4; ++r)
                    Kb[(size_t)(m0 + r) * D + (n - D)] = f2bf(a[r] + bv);
            } else {
                const int h = (n - 2 * D) >> 7;
                const int dh = (n - 2 * D) & 127;
                const int bb = m0 >> 9;
                const int t = m0 & 511;
                ushort4 pk;
                pk.x = f2bf(a[0] + bv); pk.y = f2bf(a[1] + bv);
                pk.z = f2bf(a[2] + bv); pk.w = f2bf(a[3] + bv);
                *(ushort4*)&Vt[((size_t)(bb * H + h) * DH + dh) * TL + t] = pk;
            }
        }
    }
}

// ---------------- MFMA flash attention -------------------------------------
#define LSW16(r, g) ((((r) << 4) + ((g) ^ ((r) & 7))) << 3)
#define LSW8(r, g) ((((r) << 3) + ((g) ^ ((r) & 7))) << 3)

__global__ __launch_bounds__(256, 2) void attn_mfma(
    const ushort_t* __restrict__ Qb, const ushort_t* __restrict__ Kb,
    const ushort_t* __restrict__ Vt, ushort_t* __restrict__ Ab) {
    __shared__ ushort_t Qs[64 * 128];
    __shared__ ushort_t Ks[64 * 128];
    __shared__ ushort_t Vts[128 * 64];
    __shared__ ushort_t Ps[64 * 72];

    const int q0 = blockIdx.x * 64;
    const int bh = blockIdx.y;
    const int b = bh >> 3;
    const int h = bh & 7;
    const int tid = threadIdx.x;
    const int lane = tid & 63;
    const int w = tid >> 6;
    const int fr = lane & 15;
    const int fq = lane >> 4;

    const float slope = exp2f(-(float)(h + 1));

#pragma unroll
    for (int kk = 0; kk < 4; ++kk) {
        int s = tid + kk * 256;
        int r = s >> 4, gp = s & 15, gl = gp ^ (r & 7);
        gload_lds16(Qb + (size_t)(b * TL + q0 + r) * D + h * DH + gl * 8,
                    &Qs[s * 8]);
    }

    f32x4 o8[8];
    float m_i[4], l_i[4];
#pragma unroll
    for (int nt = 0; nt < 8; ++nt) o8[nt] = (f32x4){0.f, 0.f, 0.f, 0.f};
#pragma unroll
    for (int r = 0; r < 4; ++r) { m_i[r] = -1e30f; l_i[r] = 0.f; }

    for (int kt = 0; kt < TL / 64; ++kt) {
        __syncthreads();
#pragma unroll
        for (int kk = 0; kk < 4; ++kk) {
            int s = tid + kk * 256;
            int r = s >> 4, gp = s & 15, gl = gp ^ (r & 7);
            gload_lds16(Kb + (size_t)(b * TL + kt * 64 + r) * D + h * DH + gl * 8,
                        &Ks[s * 8]);
        }
#pragma unroll
        for (int kk = 0; kk < 4; ++kk) {
            int s = tid + kk * 256;
            int r = s >> 3, gp = s & 7, gl = gp ^ (r & 7);
            gload_lds16(Vt + ((size_t)bh * DH + r) * TL + kt * 64 + gl * 8,
                        &Vts[s * 8]);
        }
        __syncthreads();

        f32x4 sacc[4];
#pragma unroll
        for (int jt = 0; jt < 4; ++jt) sacc[jt] = (f32x4){0.f, 0.f, 0.f, 0.f};
#pragma unroll
        for (int s4 = 0; s4 < 4; ++s4) {
            bf16x8 aq = *(const bf16x8*)&Qs[LSW16(w * 16 + fr, s4 * 4 + fq)];
#pragma unroll
            for (int jt = 0; jt < 4; ++jt) {
                bf16x8 kb = *(const bf16x8*)&Ks[LSW16(jt * 16 + fr, s4 * 4 + fq)];
                sacc[jt] = __builtin_amdgcn_mfma_f32_16x16x32_bf16(
                    aq, kb, sacc[jt], 0, 0, 0);
            }
        }

        const int iq = q0 + w * 16 + fq * 4;
        const int jk = kt * 64 + fr;
        float al[4];
#pragma unroll
        for (int r = 0; r < 4; ++r) {
            float sv[4];
#pragma unroll
            for (int jt = 0; jt < 4; ++jt)
                sv[jt] = sacc[jt][r] -
                         slope * fabsf((float)(iq + r - jk - jt * 16));
            float mx = fmaxf(fmaxf(sv[0], sv[1]), fmaxf(sv[2], sv[3]));
            mx = fmaxf(mx, __shfl_xor(mx, 1));
            mx = fmaxf(mx, __shfl_xor(mx, 2));
            mx = fmaxf(mx, __shfl_xor(mx, 4));
            mx = fmaxf(mx, __shfl_xor(mx, 8));
            float mnew = fmaxf(m_i[r], mx);
            al[r] = __expf(m_i[r] - mnew);
            float rs = 0.f;
#pragma unroll
            for (int jt = 0; jt < 4; ++jt) {
                sv[jt] = __expf(sv[jt] - mnew);
                rs += sv[jt];
            }
            rs += __shfl_xor(rs, 1);
            rs += __shfl_xor(rs, 2);
            rs += __shfl_xor(rs, 4);
            rs += __shfl_xor(rs, 8);
            l_i[r] = l_i[r] * al[r] + rs;
            m_i[r] = mnew;
            const int prow = w * 16 + fq * 4 + r;
#pragma unroll
            for (int jt = 0; jt < 4; ++jt)
                Ps[prow * 72 + jt * 16 + fr] = f2bf(sv[jt]);
        }
#pragma unroll
        for (int nt = 0; nt < 8; ++nt)
#pragma unroll
            for (int r = 0; r < 4; ++r) o8[nt][r] *= al[r];

#pragma unroll
        for (int s2 = 0; s2 < 2; ++s2) {
            bf16x8 pa = *(const bf16x8*)&Ps[(w * 16 + fr) * 72 + s2 * 32 + fq * 8];
#pragma unroll
            for (int nt = 0; nt < 8; ++nt) {
                bf16x8 vb = *(const bf16x8*)&Vts[LSW8(nt * 16 + fr, s2 * 4 + fq)];
                o8[nt] = __builtin_amdgcn_mfma_f32_16x16x32_bf16(
                    pa, vb, o8[nt], 0, 0, 0);
            }
        }
    }

#pragma unroll
    for (int r = 0; r < 4; ++r) {
        float inv = 1.f / l_i[r];
        const size_t base = (size_t)(b * TL + q0 + w * 16 + fq * 4 + r) * D + h * DH;
#pragma unroll
        for (int nt = 0; nt < 8; ++nt)
            Ab[base + nt * 16 + fr] = f2bf(o8[nt][r] * inv);
    }
}

// ---------------- fused residual + LayerNorm (+ bf16 copy out) -------------
__global__ __launch_bounds__(256) void add_ln(const float* __restrict__ x,
                                              const float* __restrict__ y,
                                              const float* __restrict__ g,
                                              const float* __restrict__ bta,
                                              float* __restrict__ out,
                                              ushort_t* __restrict__ outb) {
    __shared__ float red[4];
    const int row = blockIdx.x;
    const int tid = threadIdx.x;
    const size_t base = (size_t)row * D + tid * 4;

    float4 xv = *(const float4*)(x + base);
    float4 yv = *(const float4*)(y + base);
    float v[4] = {xv.x + yv.x, xv.y + yv.y, xv.z + yv.z, xv.w + yv.w};

    float s = v[0] + v[1] + v[2] + v[3];
    for (int off = 32; off; off >>= 1) s += __shfl_down(s, off);
    if ((tid & 63) == 0) red[tid >> 6] = s;
    __syncthreads();
    const float mean = (red[0] + red[1] + red[2] + red[3]) * (1.f / (float)D);
    __syncthreads();

    float d0 = v[0] - mean, d1 = v[1] - mean, d2 = v[2] - mean, d3 = v[3] - mean;
    float sq = d0 * d0 + d1 * d1 + d2 * d2 + d3 * d3;
    for (int off = 32; off; off >>= 1) sq += __shfl_down(sq, off);
    if ((tid & 63) == 0) red[tid >> 6] = sq;
    __syncthreads();
    const float var = (red[0] + red[1] + red[2] + red[3]) * (1.f / (float)D);
    const float inv = rsqrtf(var + 1e-5f);

    float4 gv = *(const float4*)(g + tid * 4);
    float4 bv = *(const float4*)(bta + tid * 4);
    float4 o;
    o.x = d0 * inv * gv.x + bv.x;
    o.y = d1 * inv * gv.y + bv.y;
    o.z = d2 * inv * gv.z + bv.z;
    o.w = d3 * inv * gv.w + bv.w;
    *(float4*)(out + base) = o;
    ushort4 ob;
    ob.x = f2bf(o.x); ob.y = f2bf(o.y); ob.z = f2bf(o.z); ob.w = f2bf(o.w);
    *(ushort4*)(outb + base) = ob;
}

// ---------------- launcher -------------------------------------------------
extern "C" void kernel_launch(void* const* d_in, const int* in_sizes, int n_in,
                              void* d_out, int out_size, void* d_ws, size_t ws_size,
                              hipStream_t stream) {
    const float* x_in   = (const float*)d_in[0];
    const float* pre_w  = (const float*)d_in[1];
    const float* pre_b  = (const float*)d_in[2];
    const float* in_w   = (const float*)d_in[3];
    const float* in_b   = (const float*)d_in[4];
    const float* out_w  = (const float*)d_in[5];
    const float* out_b  = (const float*)d_in[6];
    const float* ln1_g  = (const float*)d_in[7];
    const float* ln1_b  = (const float*)d_in[8];
    const float* ff1_w  = (const float*)d_in[9];
    const float* ff1_b  = (const float*)d_in[10];
    const float* ff2_w  = (const float*)d_in[11];
    const float* ff2_b  = (const float*)d_in[12];
    const float* ln2_g  = (const float*)d_in[13];
    const float* ln2_b  = (const float*)d_in[14];
    const float* post_w = (const float*)d_in[15];
    const float* post_b = (const float*)d_in[16];

    float* X = (float*)d_ws;
    float* Y = X + (size_t)M_ROWS * D;
    ushort_t* Xb   = (ushort_t*)(Y + (size_t)M_ROWS * D);
    ushort_t* Ab   = Xb + (size_t)M_ROWS * D;
    ushort_t* Qb   = Ab + (size_t)M_ROWS * D;
    ushort_t* Kb   = Qb + (size_t)M_ROWS * D;
    ushort_t* Vt   = Kb + (size_t)M_ROWS * D;
    ushort_t* xinb = Vt + (size_t)M_ROWS * D;
    ushort_t* pwb  = xinb + (size_t)M_ROWS * 512;
    ushort_t* iwb  = pwb + (size_t)D * 512;
    ushort_t* owb  = iwb + (size_t)NL * 3 * D * D;
    ushort_t* f1wb = owb + (size_t)NL * D * D;
    ushort_t* f2wb = f1wb + (size_t)NL * DFF * D;
    ushort_t* powb = f2wb + (size_t)NL * D * DFF;

    const dim3 blk(256);

    CvtArgs ca;
    ca.s[0] = x_in;   ca.d[0] = xinb; ca.nq[0] = (M_ROWS * 512) / 4;
    ca.s[1] = pre_w;  ca.d[1] = pwb;  ca.nq[1] = (D * 512) / 4;
    ca.s[2] = in_w;   ca.d[2] = iwb;  ca.nq[2] = (NL * 3 * D * D) / 4;
    ca.s[3] = out_w;  ca.d[3] = owb;  ca.nq[3] = (NL * D * D) / 4;
    ca.s[4] = ff1_w;  ca.d[4] = f1wb; ca.nq[4] = (NL * DFF * D) / 4;
    ca.s[5] = ff2_w;  ca.d[5] = f2wb; ca.nq[5] = (NL * D * DFF) / 4;
    ca.s[6] = post_w; ca.d[6] = powb; ca.nq[6] = (D * D) / 4;
    {
        long long total = 0;
        for (int i = 0; i < 7; ++i) total += ca.nq[i];
        long long cum = 0;
        ca.bstart[0] = 0;
        for (int i = 0; i < 7; ++i) {
            cum += ca.nq[i];
            ca.bstart[i + 1] = (int)((cum * 4096) / total);
        }
        ca.bstart[7] = 4096;
    }
    cvt_all<<<4096, blk, 0, stream>>>(ca);

    const dim3 gN64(D / 64, M_ROWS / 128);          // 512 blocks
    const dim3 gQKV(3 * D / 128, M_ROWS / 128);     // 768 blocks

    gemm_n64<<<gN64, blk, 0, stream>>>(xinb, pwb, pre_b, X, Xb,
                                       M_ROWS, D, 512, 0);

    for (int l = 0; l < NL; ++l) {
        gemm_qkv<<<gQKV, blk, 0, stream>>>(Xb, iwb + (size_t)l * 3 * D * D,
                                           in_b + (size_t)l * 3 * D,
                                           Qb, Kb, Vt, D);
        attn_mfma<<<dim3(TL / 64, B * H), blk, 0, stream>>>(Qb, Kb, Vt, Ab);
        gemm_n64<<<gN64, blk, 0, stream>>>(Ab, owb + (size_t)l * D * D,
                                           out_b + (size_t)l * D, Y, nullptr,
                                           M_ROWS, D, D, 0);
        add_ln<<<dim3(M_ROWS), blk, 0, stream>>>(X, Y, ln1_g + (size_t)l * D,
                                                 ln1_b + (size_t)l * D, X, Xb);
        gemm_n64<<<gN64, blk, 0, stream>>>(Xb, f1wb + (size_t)l * DFF * D,
                                           ff1_b + (size_t)l * DFF, nullptr, Ab,
                                           M_ROWS, DFF, D, 1);
        gemm_n64<<<gN64, blk, 0, stream>>>(Ab, f2wb + (size_t)l * D * DFF,
                                           ff2_b + (size_t)l * D, Y, nullptr,
                                           M_ROWS, D, DFF, 0);
        add_ln<<<dim3(M_ROWS), blk, 0, stream>>>(X, Y, ln2_g + (size_t)l * D,
                                                 ln2_b + (size_t)l * D, X, Xb);
    }

    gemm_n64<<<gN64, blk, 0, stream>>>(Xb, powb, post_b, (float*)d_out, nullptr,
                                       M_ROWS, D, D, 0);
}